// Round 1
// baseline (2505.727 us; speedup 1.0000x reference)
//
#include <hip/hip_runtime.h>

constexpr int F  = 128;   // input feature dim
constexpr int H1 = 256;
constexpr int H2 = 128;
constexpr int C  = 40;

__device__ __forceinline__ float wave_sum64(float v) {
#pragma unroll
    for (int off = 32; off > 0; off >>= 1) v += __shfl_xor(v, off, 64);
    return v;
}

// ---------------------------------------------------------------------------
// Edge kernel: per edge e with segment s = seg[e]
//   nb    = l2norm(neighbor_x[e])          -> atomicAdd into Sx[s]   (+cnt[s])
//   n_h   = nb @ W1 + b1                   -> atomicAdd relu into S2[s]
//   n_h2  = n_h @ W2 + b2                  -> atomicAdd relu into S4[s]
// ---------------------------------------------------------------------------
template <int TILE>
__global__ __launch_bounds__(256) void edge_kernel(
    const float* __restrict__ nbx, const int* __restrict__ seg,
    const float* __restrict__ W1, const float* __restrict__ b1,
    const float* __restrict__ W2, const float* __restrict__ b2,
    float* __restrict__ Sx, float* __restrict__ S2, float* __restrict__ S4,
    float* __restrict__ cnt, int E)
{
    __shared__ float s_nb[TILE][F];
    __shared__ float s_nh[TILE][H1];
    __shared__ int   s_seg[TILE];

    const int tid  = threadIdx.x;
    const int e0   = blockIdx.x * TILE;
    const int wave = tid >> 6;
    const int lane = tid & 63;

    if (tid < TILE) {
        const int e = e0 + tid;
        s_seg[tid] = (e < E) ? seg[e] : -1;
    }

    // Phase A: load rows, l2-normalize, scatter nb into Sx
#pragma unroll
    for (int r = wave; r < TILE; r += 4) {
        const int e = e0 + r;
        float v0 = 0.f, v1 = 0.f;
        if (e < E) {
            v0 = nbx[(size_t)e * F + lane];
            v1 = nbx[(size_t)e * F + 64 + lane];
        }
        const float ss = wave_sum64(v0 * v0 + v1 * v1);
        const float sc = 1.0f / fmaxf(sqrtf(ss), 1e-12f);
        v0 *= sc; v1 *= sc;
        s_nb[r][lane]      = v0;
        s_nb[r][64 + lane] = v1;
        if (e < E) {
            const int sg = seg[e];
            atomicAdd(&Sx[(size_t)sg * F + lane],      v0);
            atomicAdd(&Sx[(size_t)sg * F + 64 + lane], v1);
            if (lane == 0) atomicAdd(&cnt[sg], 1.0f);
        }
    }
    __syncthreads();

    // Phase B: n_h[e][j] = nb[e] . W1[:,j] + b1[j]; thread j = tid (256 cols)
    {
        const int j = tid;
        float acc[TILE];
#pragma unroll
        for (int e = 0; e < TILE; ++e) acc[e] = 0.f;
        for (int f = 0; f < F; f += 4) {
            const float w0 = W1[(size_t)(f + 0) * H1 + j];
            const float w1 = W1[(size_t)(f + 1) * H1 + j];
            const float w2 = W1[(size_t)(f + 2) * H1 + j];
            const float w3 = W1[(size_t)(f + 3) * H1 + j];
#pragma unroll
            for (int e = 0; e < TILE; ++e) {
                const float4 a = *(const float4*)&s_nb[e][f];
                acc[e] = fmaf(a.x, w0, fmaf(a.y, w1, fmaf(a.z, w2, fmaf(a.w, w3, acc[e]))));
            }
        }
        const float bj = b1[j];
#pragma unroll
        for (int e = 0; e < TILE; ++e) {
            const float v = acc[e] + bj;
            s_nh[e][j] = v;
            const int sg = s_seg[e];
            if (sg >= 0) atomicAdd(&S2[(size_t)sg * H1 + j], fmaxf(v, 0.f));
        }
    }
    __syncthreads();

    // Phase C: n_h2[e][j] = n_h[e] . W2[:,j] + b2[j]; threads = 2 groups x 128 cols
    {
        const int p = tid >> 7;
        const int j = tid & 127;
        float acc[TILE / 2];
#pragma unroll
        for (int i = 0; i < TILE / 2; ++i) acc[i] = 0.f;
        for (int k = 0; k < H1; k += 4) {
            const float w0 = W2[(size_t)(k + 0) * H2 + j];
            const float w1 = W2[(size_t)(k + 1) * H2 + j];
            const float w2 = W2[(size_t)(k + 2) * H2 + j];
            const float w3 = W2[(size_t)(k + 3) * H2 + j];
#pragma unroll
            for (int i = 0; i < TILE / 2; ++i) {
                const float4 a = *(const float4*)&s_nh[2 * i + p][k];
                acc[i] = fmaf(a.x, w0, fmaf(a.y, w1, fmaf(a.z, w2, fmaf(a.w, w3, acc[i]))));
            }
        }
        const float bj = b2[j];
#pragma unroll
        for (int i = 0; i < TILE / 2; ++i) {
            const int e  = 2 * i + p;
            const int sg = s_seg[e];
            if (sg >= 0) atomicAdd(&S4[(size_t)sg * H2 + j], fmaxf(acc[i] + bj, 0.f));
        }
    }
}

// ---------------------------------------------------------------------------
// Node kernel: full per-node chain.
//   xn = l2norm(x);  h = xn@W1+b1;  S1 = Sx@W1 + cnt*b1
//   x1 = relu(h + .9*S1); x2 = .9*(x1 + S2) + .1*h
//   h2 = x2@W2+b2;  S3 = S1@W2 + cnt*b2
//   x3 = relu(h2 + .9*S3); x4 = .9*(x3 + S4) + .1*h2
//   out = x4@Wc + bc
// ---------------------------------------------------------------------------
template <int TILE>
__global__ __launch_bounds__(256) void node_kernel(
    const float* __restrict__ x,
    const float* __restrict__ W1, const float* __restrict__ b1,
    const float* __restrict__ W2, const float* __restrict__ b2,
    const float* __restrict__ Wc, const float* __restrict__ bc,
    const float* __restrict__ Sx, const float* __restrict__ S2,
    const float* __restrict__ S4, const float* __restrict__ cnt,
    float* __restrict__ out, int N)
{
    __shared__ float s_xn[TILE][F];
    __shared__ float s_sx[TILE][F];
    __shared__ float s_x2[TILE][H1];
    __shared__ float s_s1[TILE][H1];
    __shared__ float s_x4[TILE][H2];
    __shared__ float s_cnt[TILE];

    const int tid  = threadIdx.x;
    const int n0   = blockIdx.x * TILE;
    const int wave = tid >> 6;
    const int lane = tid & 63;

    // Phase A: load x rows (l2norm) and Sx rows
#pragma unroll
    for (int r = wave; r < TILE; r += 4) {
        const int n = n0 + r;
        float v0 = 0.f, v1 = 0.f, u0 = 0.f, u1 = 0.f, c = 0.f;
        if (n < N) {
            v0 = x[(size_t)n * F + lane];
            v1 = x[(size_t)n * F + 64 + lane];
            u0 = Sx[(size_t)n * F + lane];
            u1 = Sx[(size_t)n * F + 64 + lane];
            c  = cnt[n];
        }
        const float ss = wave_sum64(v0 * v0 + v1 * v1);
        const float sc = 1.0f / fmaxf(sqrtf(ss), 1e-12f);
        s_xn[r][lane]      = v0 * sc;
        s_xn[r][64 + lane] = v1 * sc;
        s_sx[r][lane]      = u0;
        s_sx[r][64 + lane] = u1;
        if (lane == 0) s_cnt[r] = c;
    }
    __syncthreads();

    // Phase B: h and S1 (both vs W1), then x2
    {
        const int j = tid;
        float ah[TILE], as[TILE];
#pragma unroll
        for (int e = 0; e < TILE; ++e) { ah[e] = 0.f; as[e] = 0.f; }
        for (int f = 0; f < F; f += 4) {
            const float w0 = W1[(size_t)(f + 0) * H1 + j];
            const float w1 = W1[(size_t)(f + 1) * H1 + j];
            const float w2 = W1[(size_t)(f + 2) * H1 + j];
            const float w3 = W1[(size_t)(f + 3) * H1 + j];
#pragma unroll
            for (int e = 0; e < TILE; ++e) {
                const float4 a = *(const float4*)&s_xn[e][f];
                const float4 b = *(const float4*)&s_sx[e][f];
                ah[e] = fmaf(a.x, w0, fmaf(a.y, w1, fmaf(a.z, w2, fmaf(a.w, w3, ah[e]))));
                as[e] = fmaf(b.x, w0, fmaf(b.y, w1, fmaf(b.z, w2, fmaf(b.w, w3, as[e]))));
            }
        }
        const float bj = b1[j];
#pragma unroll
        for (int e = 0; e < TILE; ++e) {
            const int n = n0 + e;
            if (n < N) {
                const float h  = ah[e] + bj;
                const float S1 = as[e] + s_cnt[e] * bj;
                const float x1 = fmaxf(h + 0.9f * S1, 0.f);
                const float x2v = 0.9f * (x1 + S2[(size_t)n * H1 + j]) + 0.1f * h;
                s_x2[e][j] = x2v;
                s_s1[e][j] = S1;
            } else {
                s_x2[e][j] = 0.f;
                s_s1[e][j] = 0.f;
            }
        }
    }
    __syncthreads();

    // Phase C: h2 and S3 (both vs W2), then x4
    {
        const int p = tid >> 7;
        const int j = tid & 127;
        float a2[TILE / 2], a3[TILE / 2];
#pragma unroll
        for (int i = 0; i < TILE / 2; ++i) { a2[i] = 0.f; a3[i] = 0.f; }
        for (int k = 0; k < H1; k += 4) {
            const float w0 = W2[(size_t)(k + 0) * H2 + j];
            const float w1 = W2[(size_t)(k + 1) * H2 + j];
            const float w2 = W2[(size_t)(k + 2) * H2 + j];
            const float w3 = W2[(size_t)(k + 3) * H2 + j];
#pragma unroll
            for (int i = 0; i < TILE / 2; ++i) {
                const float4 a = *(const float4*)&s_x2[2 * i + p][k];
                const float4 b = *(const float4*)&s_s1[2 * i + p][k];
                a2[i] = fmaf(a.x, w0, fmaf(a.y, w1, fmaf(a.z, w2, fmaf(a.w, w3, a2[i]))));
                a3[i] = fmaf(b.x, w0, fmaf(b.y, w1, fmaf(b.z, w2, fmaf(b.w, w3, a3[i]))));
            }
        }
        const float bj = b2[j];
#pragma unroll
        for (int i = 0; i < TILE / 2; ++i) {
            const int e = 2 * i + p;
            const int n = n0 + e;
            if (n < N) {
                const float h2 = a2[i] + bj;
                const float S3 = a3[i] + s_cnt[e] * bj;
                const float x3 = fmaxf(h2 + 0.9f * S3, 0.f);
                s_x4[e][j] = 0.9f * (x3 + S4[(size_t)n * H2 + j]) + 0.1f * h2;
            } else {
                s_x4[e][j] = 0.f;
            }
        }
    }
    __syncthreads();

    // Phase D: out = x4 @ Wc + bc   (tiny: 128x40)
    if (tid < 240) {
        const int g = tid / 40;   // 0..5 row groups
        const int c = tid % 40;
        float acc[3] = {0.f, 0.f, 0.f};
        for (int f = 0; f < H2; ++f) {
            const float w = Wc[(size_t)f * C + c];
#pragma unroll
            for (int i = 0; i < 3; ++i) {
                const int r = g + 6 * i;
                if (r < TILE) acc[i] += s_x4[r][f] * w;
            }
        }
        const float bcc = bc[c];
#pragma unroll
        for (int i = 0; i < 3; ++i) {
            const int r = g + 6 * i;
            const int n = n0 + r;
            if (r < TILE && n < N) out[(size_t)n * C + c] = acc[i] + bcc;
        }
    }
}

extern "C" void kernel_launch(void* const* d_in, const int* in_sizes, int n_in,
                              void* d_out, int out_size, void* d_ws, size_t ws_size,
                              hipStream_t stream) {
    const float* x   = (const float*)d_in[0];
    const float* nbx = (const float*)d_in[1];
    const float* W1  = (const float*)d_in[2];
    const float* b1  = (const float*)d_in[3];
    const float* W2  = (const float*)d_in[4];
    const float* b2  = (const float*)d_in[5];
    const float* Wc  = (const float*)d_in[6];
    const float* bc  = (const float*)d_in[7];
    const int*   seg = (const int*)d_in[8];

    const int N = in_sizes[0] / F;   // 50000
    const int E = in_sizes[8];       // 600000
    float* out = (float*)d_out;

    // workspace layout (floats): Sx[N*F] | S2[N*H1] | S4[N*H2] | cnt[N]
    float* Sx  = (float*)d_ws;
    float* S2  = Sx + (size_t)N * F;
    float* S4  = S2 + (size_t)N * H1;
    float* cnt = S4 + (size_t)N * H2;
    const size_t ws_need = ((size_t)N * (F + H1 + H2) + (size_t)N) * sizeof(float);
    hipMemsetAsync(d_ws, 0, ws_need, stream);

    constexpr int TILE_E = 32;
    constexpr int TILE_N = 16;
    edge_kernel<TILE_E><<<(E + TILE_E - 1) / TILE_E, 256, 0, stream>>>(
        nbx, seg, W1, b1, W2, b2, Sx, S2, S4, cnt, E);
    node_kernel<TILE_N><<<(N + TILE_N - 1) / TILE_N, 256, 0, stream>>>(
        x, W1, b1, W2, b2, Wc, bc, Sx, S2, S4, cnt, out, N);
}

// Round 2
// 1607.302 us; speedup vs baseline: 1.5590x; 1.5590x over previous
//
#include <hip/hip_runtime.h>

constexpr int F  = 128;   // input feature dim
constexpr int H1 = 256;
constexpr int H2 = 128;
constexpr int C  = 40;

using f32x4 = __attribute__((ext_vector_type(4))) float;
using f16x8 = __attribute__((ext_vector_type(8))) _Float16;

__device__ __forceinline__ float wave_sum64(float v) {
#pragma unroll
    for (int off = 32; off > 0; off >>= 1) v += __shfl_xor(v, off, 64);
    return v;
}

// ---------------------------------------------------------------------------
// Weight prep: transpose + fp16-convert W1, W2 into workspace.
//   W1t[j][f] = W1[f][j]   (256 x 128)
//   W2t[j][k] = W2[k][j]   (128 x 256)
// ---------------------------------------------------------------------------
__global__ __launch_bounds__(256) void prep_weights(
    const float* __restrict__ W1, const float* __restrict__ W2,
    _Float16* __restrict__ W1t, _Float16* __restrict__ W2t)
{
    const int i = blockIdx.x * 256 + threadIdx.x;   // 32768 total
    if (i < H1 * F) {   // W1t: j = i>>7 (256), f = i&127
        const int j = i >> 7, f = i & 127;
        W1t[i] = (_Float16)W1[(size_t)f * H1 + j];
    }
    if (i < H2 * H1) {  // W2t: j = i>>8 (128), k = i&255
        const int j = i >> 8, k = i & 255;
        W2t[i] = (_Float16)W2[(size_t)k * H2 + j];
    }
}

// ---------------------------------------------------------------------------
// Edge kernel v2 (MFMA): 64 edges/block, 4 waves, NO barriers.
// Wave w owns rows [w*16, w*16+16):
//   Phase A: load nbx rows, l2norm (fp32), fp32 atomics into Sx, fp16 into LDS
//   Phase B: n_h = A @ W1t^T via mfma_f32_16x16x32_f16; relu->S2 atomics;
//            n_h (pre-relu) fp16 into LDS
//   Phase C: n_h2 = n_h @ W2t^T via MFMA; relu->S4 atomics
// MFMA layouts (gfx950 16x16x32):
//   A: lane holds row=lane&15, k=(lane>>4)*8 .. +8 (contiguous 16B)
//   B: lane holds col=lane&15, k=(lane>>4)*8 .. +8 (contiguous 16B in W*t)
//   C: col=lane&15, row=(lane>>4)*4 + reg
// ---------------------------------------------------------------------------
__global__ __launch_bounds__(256) void edge_kernel2(
    const float* __restrict__ nbx, const int* __restrict__ seg,
    const _Float16* __restrict__ W1t, const float* __restrict__ b1,
    const _Float16* __restrict__ W2t, const float* __restrict__ b2,
    float* __restrict__ Sx, float* __restrict__ S2, float* __restrict__ S4,
    float* __restrict__ cnt, int E)
{
    // +8 fp16 row pad (16B) -> 2-way bank aliasing only (free)
    __shared__ _Float16 s_A[64][136];
    __shared__ _Float16 s_nh[64][264];
    __shared__ int s_seg[64];

    const int tid  = threadIdx.x;
    const int lane = tid & 63;
    const int w    = tid >> 6;
    const int e0   = blockIdx.x * 64;
    const int mrow = lane & 15;
    const int kgrp = lane >> 4;

    // ---- Phase A ----
#pragma unroll 4
    for (int i = 0; i < 16; ++i) {
        const int r = w * 16 + i;
        const int e = e0 + r;
        float v0 = 0.f, v1 = 0.f;
        if (e < E) {
            v0 = nbx[(size_t)e * F + lane];
            v1 = nbx[(size_t)e * F + 64 + lane];
        }
        const float ss = wave_sum64(v0 * v0 + v1 * v1);
        const float sc = 1.0f / fmaxf(sqrtf(ss), 1e-12f);
        v0 *= sc; v1 *= sc;
        s_A[r][lane]      = (_Float16)v0;
        s_A[r][64 + lane] = (_Float16)v1;
        int sg = -1;
        if (e < E) {
            sg = seg[e];
            atomicAdd(&Sx[(size_t)sg * F + lane],      v0);
            atomicAdd(&Sx[(size_t)sg * F + 64 + lane], v1);
            if (lane == 0) atomicAdd(&cnt[sg], 1.0f);
        }
        if (lane == 0) s_seg[r] = sg;
    }
    // no __syncthreads: each wave only touches its own 16 rows

    int sgs[4];
#pragma unroll
    for (int r = 0; r < 4; ++r) sgs[r] = s_seg[w * 16 + kgrp * 4 + r];

    // ---- Phase B: GEMM1 (M=16/wave, N=256, K=128) ----
    f16x8 a1[4];
#pragma unroll
    for (int kk = 0; kk < 4; ++kk)
        a1[kk] = *(const f16x8*)&s_A[w * 16 + mrow][kk * 32 + kgrp * 8];

#pragma unroll
    for (int n = 0; n < 16; ++n) {
        const int col = n * 16 + mrow;
        f32x4 acc = {0.f, 0.f, 0.f, 0.f};
#pragma unroll
        for (int kk = 0; kk < 4; ++kk) {
            const f16x8 b = *(const f16x8*)&W1t[(size_t)col * F + kk * 32 + kgrp * 8];
            acc = __builtin_amdgcn_mfma_f32_16x16x32_f16(a1[kk], b, acc, 0, 0, 0);
        }
        const float bj = b1[col];
#pragma unroll
        for (int r = 0; r < 4; ++r) {
            const float v = acc[r] + bj;
            s_nh[w * 16 + kgrp * 4 + r][col] = (_Float16)v;
            if (sgs[r] >= 0)
                atomicAdd(&S2[(size_t)sgs[r] * H1 + col], fmaxf(v, 0.f));
        }
    }

    // ---- Phase C: GEMM2 (M=16/wave, N=128, K=256) ----
    f16x8 a2[8];
#pragma unroll
    for (int k0 = 0; k0 < 8; ++k0)
        a2[k0] = *(const f16x8*)&s_nh[w * 16 + mrow][k0 * 32 + kgrp * 8];

#pragma unroll
    for (int n = 0; n < 8; ++n) {
        const int col = n * 16 + mrow;
        f32x4 acc = {0.f, 0.f, 0.f, 0.f};
#pragma unroll
        for (int k0 = 0; k0 < 8; ++k0) {
            const f16x8 b = *(const f16x8*)&W2t[(size_t)col * H1 + k0 * 32 + kgrp * 8];
            acc = __builtin_amdgcn_mfma_f32_16x16x32_f16(a2[k0], b, acc, 0, 0, 0);
        }
        const float bj = b2[col];
#pragma unroll
        for (int r = 0; r < 4; ++r) {
            const float v = acc[r] + bj;
            if (sgs[r] >= 0)
                atomicAdd(&S4[(size_t)sgs[r] * H2 + col], fmaxf(v, 0.f));
        }
    }
}

// ---------------------------------------------------------------------------
// Node kernel (unchanged from round 1): full per-node chain in fp32.
// ---------------------------------------------------------------------------
template <int TILE>
__global__ __launch_bounds__(256) void node_kernel(
    const float* __restrict__ x,
    const float* __restrict__ W1, const float* __restrict__ b1,
    const float* __restrict__ W2, const float* __restrict__ b2,
    const float* __restrict__ Wc, const float* __restrict__ bc,
    const float* __restrict__ Sx, const float* __restrict__ S2,
    const float* __restrict__ S4, const float* __restrict__ cnt,
    float* __restrict__ out, int N)
{
    __shared__ float s_xn[TILE][F];
    __shared__ float s_sx[TILE][F];
    __shared__ float s_x2[TILE][H1];
    __shared__ float s_s1[TILE][H1];
    __shared__ float s_x4[TILE][H2];
    __shared__ float s_cnt[TILE];

    const int tid  = threadIdx.x;
    const int n0   = blockIdx.x * TILE;
    const int wave = tid >> 6;
    const int lane = tid & 63;

#pragma unroll
    for (int r = wave; r < TILE; r += 4) {
        const int n = n0 + r;
        float v0 = 0.f, v1 = 0.f, u0 = 0.f, u1 = 0.f, c = 0.f;
        if (n < N) {
            v0 = x[(size_t)n * F + lane];
            v1 = x[(size_t)n * F + 64 + lane];
            u0 = Sx[(size_t)n * F + lane];
            u1 = Sx[(size_t)n * F + 64 + lane];
            c  = cnt[n];
        }
        const float ss = wave_sum64(v0 * v0 + v1 * v1);
        const float sc = 1.0f / fmaxf(sqrtf(ss), 1e-12f);
        s_xn[r][lane]      = v0 * sc;
        s_xn[r][64 + lane] = v1 * sc;
        s_sx[r][lane]      = u0;
        s_sx[r][64 + lane] = u1;
        if (lane == 0) s_cnt[r] = c;
    }
    __syncthreads();

    {
        const int j = tid;
        float ah[TILE], as[TILE];
#pragma unroll
        for (int e = 0; e < TILE; ++e) { ah[e] = 0.f; as[e] = 0.f; }
        for (int f = 0; f < F; f += 4) {
            const float w0 = W1[(size_t)(f + 0) * H1 + j];
            const float w1 = W1[(size_t)(f + 1) * H1 + j];
            const float w2 = W1[(size_t)(f + 2) * H1 + j];
            const float w3 = W1[(size_t)(f + 3) * H1 + j];
#pragma unroll
            for (int e = 0; e < TILE; ++e) {
                const float4 a = *(const float4*)&s_xn[e][f];
                const float4 b = *(const float4*)&s_sx[e][f];
                ah[e] = fmaf(a.x, w0, fmaf(a.y, w1, fmaf(a.z, w2, fmaf(a.w, w3, ah[e]))));
                as[e] = fmaf(b.x, w0, fmaf(b.y, w1, fmaf(b.z, w2, fmaf(b.w, w3, as[e]))));
            }
        }
        const float bj = b1[j];
#pragma unroll
        for (int e = 0; e < TILE; ++e) {
            const int n = n0 + e;
            if (n < N) {
                const float h  = ah[e] + bj;
                const float S1 = as[e] + s_cnt[e] * bj;
                const float x1 = fmaxf(h + 0.9f * S1, 0.f);
                const float x2v = 0.9f * (x1 + S2[(size_t)n * H1 + j]) + 0.1f * h;
                s_x2[e][j] = x2v;
                s_s1[e][j] = S1;
            } else {
                s_x2[e][j] = 0.f;
                s_s1[e][j] = 0.f;
            }
        }
    }
    __syncthreads();

    {
        const int p = tid >> 7;
        const int j = tid & 127;
        float a2[TILE / 2], a3[TILE / 2];
#pragma unroll
        for (int i = 0; i < TILE / 2; ++i) { a2[i] = 0.f; a3[i] = 0.f; }
        for (int k = 0; k < H1; k += 4) {
            const float w0 = W2[(size_t)(k + 0) * H2 + j];
            const float w1 = W2[(size_t)(k + 1) * H2 + j];
            const float w2 = W2[(size_t)(k + 2) * H2 + j];
            const float w3 = W2[(size_t)(k + 3) * H2 + j];
#pragma unroll
            for (int i = 0; i < TILE / 2; ++i) {
                const float4 a = *(const float4*)&s_x2[2 * i + p][k];
                const float4 b = *(const float4*)&s_s1[2 * i + p][k];
                a2[i] = fmaf(a.x, w0, fmaf(a.y, w1, fmaf(a.z, w2, fmaf(a.w, w3, a2[i]))));
                a3[i] = fmaf(b.x, w0, fmaf(b.y, w1, fmaf(b.z, w2, fmaf(b.w, w3, a3[i]))));
            }
        }
        const float bj = b2[j];
#pragma unroll
        for (int i = 0; i < TILE / 2; ++i) {
            const int e = 2 * i + p;
            const int n = n0 + e;
            if (n < N) {
                const float h2 = a2[i] + bj;
                const float S3 = a3[i] + s_cnt[e] * bj;
                const float x3 = fmaxf(h2 + 0.9f * S3, 0.f);
                s_x4[e][j] = 0.9f * (x3 + S4[(size_t)n * H2 + j]) + 0.1f * h2;
            } else {
                s_x4[e][j] = 0.f;
            }
        }
    }
    __syncthreads();

    if (tid < 240) {
        const int g = tid / 40;
        const int c = tid % 40;
        float acc[3] = {0.f, 0.f, 0.f};
        for (int f = 0; f < H2; ++f) {
            const float w = Wc[(size_t)f * C + c];
#pragma unroll
            for (int i = 0; i < 3; ++i) {
                const int r = g + 6 * i;
                if (r < TILE) acc[i] += s_x4[r][f] * w;
            }
        }
        const float bcc = bc[c];
#pragma unroll
        for (int i = 0; i < 3; ++i) {
            const int r = g + 6 * i;
            const int n = n0 + r;
            if (r < TILE && n < N) out[(size_t)n * C + c] = acc[i] + bcc;
        }
    }
}

extern "C" void kernel_launch(void* const* d_in, const int* in_sizes, int n_in,
                              void* d_out, int out_size, void* d_ws, size_t ws_size,
                              hipStream_t stream) {
    const float* x   = (const float*)d_in[0];
    const float* nbx = (const float*)d_in[1];
    const float* W1  = (const float*)d_in[2];
    const float* b1  = (const float*)d_in[3];
    const float* W2  = (const float*)d_in[4];
    const float* b2  = (const float*)d_in[5];
    const float* Wc  = (const float*)d_in[6];
    const float* bc  = (const float*)d_in[7];
    const int*   seg = (const int*)d_in[8];

    const int N = in_sizes[0] / F;   // 50000
    const int E = in_sizes[8];       // 600000
    float* out = (float*)d_out;

    // workspace: Sx[N*F] | S2[N*H1] | S4[N*H2] | cnt[N] | W1t fp16 | W2t fp16
    float* Sx  = (float*)d_ws;
    float* S2  = Sx + (size_t)N * F;
    float* S4  = S2 + (size_t)N * H1;
    float* cnt = S4 + (size_t)N * H2;
    const size_t zero_floats = (size_t)N * (F + H1 + H2) + (size_t)N;
    _Float16* W1t = (_Float16*)((char*)d_ws + ((zero_floats * 4 + 15) & ~(size_t)15));
    _Float16* W2t = W1t + (size_t)H1 * F;

    hipMemsetAsync(d_ws, 0, zero_floats * sizeof(float), stream);
    prep_weights<<<128, 256, 0, stream>>>(W1, W2, W1t, W2t);

    edge_kernel2<<<(E + 63) / 64, 256, 0, stream>>>(
        nbx, seg, W1t, b1, W2t, b2, Sx, S2, S4, cnt, E);
    node_kernel<16><<<(N + 15) / 16, 256, 0, stream>>>(
        x, W1, b1, W2, b2, Wc, bc, Sx, S2, S4, cnt, out, N);
}

// Round 3
// 1410.178 us; speedup vs baseline: 1.7769x; 1.1398x over previous
//
#include <hip/hip_runtime.h>

constexpr int F  = 128;   // input feature dim
constexpr int H1 = 256;
constexpr int H2 = 128;
constexpr int C  = 40;

using f32x4 = __attribute__((ext_vector_type(4))) float;
using f16x8 = __attribute__((ext_vector_type(8))) _Float16;

__device__ __forceinline__ float wave_sum64(float v) {
#pragma unroll
    for (int off = 32; off > 0; off >>= 1) v += __shfl_xor(v, off, 64);
    return v;
}

// one dword-granularity L2 atomic covering TWO f16 values
__device__ __forceinline__ void atomic_pk(_Float16* addr, float a, float b) {
    union { _Float16 h[2]; unsigned u; } p;
    p.h[0] = (_Float16)a;
    p.h[1] = (_Float16)b;
    asm volatile("global_atomic_pk_add_f16 %0, %1, off" :: "v"(addr), "v"(p.u));
}

// ---------------------------------------------------------------------------
// Weight prep: transpose + fp16-convert W1, W2 into workspace.
//   W1t[j][f] = W1[f][j]   (256 x 128)
//   W2t[j][k] = W2[k][j]   (128 x 256)
// ---------------------------------------------------------------------------
__global__ __launch_bounds__(256) void prep_weights(
    const float* __restrict__ W1, const float* __restrict__ W2,
    _Float16* __restrict__ W1t, _Float16* __restrict__ W2t)
{
    const int i = blockIdx.x * 256 + threadIdx.x;   // 32768 total
    if (i < H1 * F) {
        const int j = i >> 7, f = i & 127;
        W1t[i] = (_Float16)W1[(size_t)f * H1 + j];
    }
    if (i < H2 * H1) {
        const int j = i >> 8, k = i & 255;
        W2t[i] = (_Float16)W2[(size_t)k * H2 + j];
    }
}

// ---------------------------------------------------------------------------
// Edge kernel v3: 64 edges/block, 4 waves, NO barriers, pk_add_f16 atomics.
// LDS: single unioned buffer s_buf[64][264]:
//   Phase A writes l2norm'd rows into cols [0,128); A-frags loaded to regs;
//   Phase B overwrites rows with n_h in cols [0,256); Phase C reads frags.
// ---------------------------------------------------------------------------
__global__ __launch_bounds__(256) void edge_kernel3(
    const float* __restrict__ nbx, const int* __restrict__ seg,
    const _Float16* __restrict__ W1t, const float* __restrict__ b1,
    const _Float16* __restrict__ W2t, const float* __restrict__ b2,
    _Float16* __restrict__ Sxh, _Float16* __restrict__ S2h,
    _Float16* __restrict__ S4h, float* __restrict__ cnt, int E)
{
    __shared__ _Float16 s_buf[64][264];   // 33.8 KB
    __shared__ int s_seg[64];

    const int tid  = threadIdx.x;
    const int lane = tid & 63;
    const int w    = tid >> 6;
    const int e0   = blockIdx.x * 64;
    const int mrow = lane & 15;
    const int kgrp = lane >> 4;

    // ---- Phase A: load, l2norm, pk-atomics into Sx, fp16 rows into LDS ----
#pragma unroll 4
    for (int i = 0; i < 16; ++i) {
        const int r = w * 16 + i;
        const int e = e0 + r;
        float v0 = 0.f, v1 = 0.f;
        if (e < E) {
            v0 = nbx[(size_t)e * F + lane];
            v1 = nbx[(size_t)e * F + 64 + lane];
        }
        const float ss = wave_sum64(v0 * v0 + v1 * v1);
        const float sc = 1.0f / fmaxf(sqrtf(ss), 1e-12f);
        v0 *= sc; v1 *= sc;
        s_buf[r][lane]      = (_Float16)v0;
        s_buf[r][64 + lane] = (_Float16)v1;
        const float p0 = __shfl_xor(v0, 1);
        const float p1 = __shfl_xor(v1, 1);
        if (e < E) {   // wave-uniform branch
            const int sg = seg[e];
            if (!(lane & 1)) {
                atomic_pk(&Sxh[(size_t)sg * F + lane],      v0, p0);
                atomic_pk(&Sxh[(size_t)sg * F + 64 + lane], v1, p1);
            }
            if (lane == 0) { atomicAdd(&cnt[sg], 1.0f); s_seg[r] = sg; }
        } else if (lane == 0) {
            s_seg[r] = -1;
        }
    }
    // no __syncthreads: each wave touches only its own 16 rows

    int sgs[4];
#pragma unroll
    for (int r = 0; r < 4; ++r) sgs[r] = s_seg[w * 16 + kgrp * 4 + r];

    // ---- Phase B: GEMM1 (M=16/wave, N=256, K=128) ----
    f16x8 a1[4];
#pragma unroll
    for (int kk = 0; kk < 4; ++kk)
        a1[kk] = *(const f16x8*)&s_buf[w * 16 + mrow][kk * 32 + kgrp * 8];

#pragma unroll
    for (int n = 0; n < 16; ++n) {
        const int col = n * 16 + mrow;
        f32x4 acc = {0.f, 0.f, 0.f, 0.f};
#pragma unroll
        for (int kk = 0; kk < 4; ++kk) {
            const f16x8 b = *(const f16x8*)&W1t[(size_t)col * F + kk * 32 + kgrp * 8];
            acc = __builtin_amdgcn_mfma_f32_16x16x32_f16(a1[kk], b, acc, 0, 0, 0);
        }
        const float bj = b1[col];
#pragma unroll
        for (int r = 0; r < 4; ++r) {
            const float v = acc[r] + bj;
            s_buf[w * 16 + kgrp * 4 + r][col] = (_Float16)v;  // n_h (pre-relu)
            const float vo = __shfl_xor(v, 1);
            if (!(mrow & 1) && sgs[r] >= 0)
                atomic_pk(&S2h[(size_t)sgs[r] * H1 + col],
                          fmaxf(v, 0.f), fmaxf(vo, 0.f));
        }
    }

    // ---- Phase C: GEMM2 (M=16/wave, N=128, K=256) ----
    f16x8 a2[8];
#pragma unroll
    for (int k0 = 0; k0 < 8; ++k0)
        a2[k0] = *(const f16x8*)&s_buf[w * 16 + mrow][k0 * 32 + kgrp * 8];

#pragma unroll
    for (int n = 0; n < 8; ++n) {
        const int col = n * 16 + mrow;
        f32x4 acc = {0.f, 0.f, 0.f, 0.f};
#pragma unroll
        for (int k0 = 0; k0 < 8; ++k0) {
            const f16x8 b = *(const f16x8*)&W2t[(size_t)col * H1 + k0 * 32 + kgrp * 8];
            acc = __builtin_amdgcn_mfma_f32_16x16x32_f16(a2[k0], b, acc, 0, 0, 0);
        }
        const float bj = b2[col];
#pragma unroll
        for (int r = 0; r < 4; ++r) {
            const float v = fmaxf(acc[r] + bj, 0.f);
            const float vo = __shfl_xor(v, 1);
            if (!(mrow & 1) && sgs[r] >= 0)
                atomic_pk(&S4h[(size_t)sgs[r] * H2 + col], v, vo);
        }
    }
}

// ---------------------------------------------------------------------------
// Node kernel: full per-node chain in fp32; S buffers now fp16.
// ---------------------------------------------------------------------------
template <int TILE>
__global__ __launch_bounds__(256) void node_kernel(
    const float* __restrict__ x,
    const float* __restrict__ W1, const float* __restrict__ b1,
    const float* __restrict__ W2, const float* __restrict__ b2,
    const float* __restrict__ Wc, const float* __restrict__ bc,
    const _Float16* __restrict__ Sxh, const _Float16* __restrict__ S2h,
    const _Float16* __restrict__ S4h, const float* __restrict__ cnt,
    float* __restrict__ out, int N)
{
    __shared__ float s_xn[TILE][F];
    __shared__ float s_sx[TILE][F];
    __shared__ float s_x2[TILE][H1];
    __shared__ float s_s1[TILE][H1];
    __shared__ float s_x4[TILE][H2];
    __shared__ float s_cnt[TILE];

    const int tid  = threadIdx.x;
    const int n0   = blockIdx.x * TILE;
    const int wave = tid >> 6;
    const int lane = tid & 63;

#pragma unroll
    for (int r = wave; r < TILE; r += 4) {
        const int n = n0 + r;
        float v0 = 0.f, v1 = 0.f, u0 = 0.f, u1 = 0.f, c = 0.f;
        if (n < N) {
            v0 = x[(size_t)n * F + lane];
            v1 = x[(size_t)n * F + 64 + lane];
            u0 = (float)Sxh[(size_t)n * F + lane];
            u1 = (float)Sxh[(size_t)n * F + 64 + lane];
            c  = cnt[n];
        }
        const float ss = wave_sum64(v0 * v0 + v1 * v1);
        const float sc = 1.0f / fmaxf(sqrtf(ss), 1e-12f);
        s_xn[r][lane]      = v0 * sc;
        s_xn[r][64 + lane] = v1 * sc;
        s_sx[r][lane]      = u0;
        s_sx[r][64 + lane] = u1;
        if (lane == 0) s_cnt[r] = c;
    }
    __syncthreads();

    {
        const int j = tid;
        float ah[TILE], as[TILE];
#pragma unroll
        for (int e = 0; e < TILE; ++e) { ah[e] = 0.f; as[e] = 0.f; }
        for (int f = 0; f < F; f += 4) {
            const float w0 = W1[(size_t)(f + 0) * H1 + j];
            const float w1 = W1[(size_t)(f + 1) * H1 + j];
            const float w2 = W1[(size_t)(f + 2) * H1 + j];
            const float w3 = W1[(size_t)(f + 3) * H1 + j];
#pragma unroll
            for (int e = 0; e < TILE; ++e) {
                const float4 a = *(const float4*)&s_xn[e][f];
                const float4 b = *(const float4*)&s_sx[e][f];
                ah[e] = fmaf(a.x, w0, fmaf(a.y, w1, fmaf(a.z, w2, fmaf(a.w, w3, ah[e]))));
                as[e] = fmaf(b.x, w0, fmaf(b.y, w1, fmaf(b.z, w2, fmaf(b.w, w3, as[e]))));
            }
        }
        const float bj = b1[j];
#pragma unroll
        for (int e = 0; e < TILE; ++e) {
            const int n = n0 + e;
            if (n < N) {
                const float h  = ah[e] + bj;
                const float S1 = as[e] + s_cnt[e] * bj;
                const float x1 = fmaxf(h + 0.9f * S1, 0.f);
                const float x2v = 0.9f * (x1 + (float)S2h[(size_t)n * H1 + j]) + 0.1f * h;
                s_x2[e][j] = x2v;
                s_s1[e][j] = S1;
            } else {
                s_x2[e][j] = 0.f;
                s_s1[e][j] = 0.f;
            }
        }
    }
    __syncthreads();

    {
        const int p = tid >> 7;
        const int j = tid & 127;
        float a2[TILE / 2], a3[TILE / 2];
#pragma unroll
        for (int i = 0; i < TILE / 2; ++i) { a2[i] = 0.f; a3[i] = 0.f; }
        for (int k = 0; k < H1; k += 4) {
            const float w0 = W2[(size_t)(k + 0) * H2 + j];
            const float w1 = W2[(size_t)(k + 1) * H2 + j];
            const float w2 = W2[(size_t)(k + 2) * H2 + j];
            const float w3 = W2[(size_t)(k + 3) * H2 + j];
#pragma unroll
            for (int i = 0; i < TILE / 2; ++i) {
                const float4 a = *(const float4*)&s_x2[2 * i + p][k];
                const float4 b = *(const float4*)&s_s1[2 * i + p][k];
                a2[i] = fmaf(a.x, w0, fmaf(a.y, w1, fmaf(a.z, w2, fmaf(a.w, w3, a2[i]))));
                a3[i] = fmaf(b.x, w0, fmaf(b.y, w1, fmaf(b.z, w2, fmaf(b.w, w3, a3[i]))));
            }
        }
        const float bj = b2[j];
#pragma unroll
        for (int i = 0; i < TILE / 2; ++i) {
            const int e = 2 * i + p;
            const int n = n0 + e;
            if (n < N) {
                const float h2 = a2[i] + bj;
                const float S3 = a3[i] + s_cnt[e] * bj;
                const float x3 = fmaxf(h2 + 0.9f * S3, 0.f);
                s_x4[e][j] = 0.9f * (x3 + (float)S4h[(size_t)n * H2 + j]) + 0.1f * h2;
            } else {
                s_x4[e][j] = 0.f;
            }
        }
    }
    __syncthreads();

    if (tid < 240) {
        const int g = tid / 40;
        const int c = tid % 40;
        float acc[3] = {0.f, 0.f, 0.f};
        for (int f = 0; f < H2; ++f) {
            const float w = Wc[(size_t)f * C + c];
#pragma unroll
            for (int i = 0; i < 3; ++i) {
                const int r = g + 6 * i;
                if (r < TILE) acc[i] += s_x4[r][f] * w;
            }
        }
        const float bcc = bc[c];
#pragma unroll
        for (int i = 0; i < 3; ++i) {
            const int r = g + 6 * i;
            const int n = n0 + r;
            if (r < TILE && n < N) out[(size_t)n * C + c] = acc[i] + bcc;
        }
    }
}

extern "C" void kernel_launch(void* const* d_in, const int* in_sizes, int n_in,
                              void* d_out, int out_size, void* d_ws, size_t ws_size,
                              hipStream_t stream) {
    const float* x   = (const float*)d_in[0];
    const float* nbx = (const float*)d_in[1];
    const float* W1  = (const float*)d_in[2];
    const float* b1  = (const float*)d_in[3];
    const float* W2  = (const float*)d_in[4];
    const float* b2  = (const float*)d_in[5];
    const float* Wc  = (const float*)d_in[6];
    const float* bc  = (const float*)d_in[7];
    const int*   seg = (const int*)d_in[8];

    const int N = in_sizes[0] / F;   // 50000
    const int E = in_sizes[8];       // 600000
    float* out = (float*)d_out;

    // workspace: Sxh[N*F] f16 | S2h[N*H1] f16 | S4h[N*H2] f16 | cnt[N] f32 |
    //            W1t f16 | W2t f16
    _Float16* Sxh = (_Float16*)d_ws;
    _Float16* S2h = Sxh + (size_t)N * F;
    _Float16* S4h = S2h + (size_t)N * H1;
    float*    cnt = (float*)(S4h + (size_t)N * H2);
    const size_t zero_bytes = (size_t)N * (F + H1 + H2) * 2 + (size_t)N * 4;
    _Float16* W1t = (_Float16*)((char*)d_ws + ((zero_bytes + 15) & ~(size_t)15));
    _Float16* W2t = W1t + (size_t)H1 * F;

    hipMemsetAsync(d_ws, 0, zero_bytes, stream);
    prep_weights<<<128, 256, 0, stream>>>(W1, W2, W1t, W2t);

    edge_kernel3<<<(E + 63) / 64, 256, 0, stream>>>(
        nbx, seg, W1t, b1, W2t, b2, Sxh, S2h, S4h, cnt, E);
    node_kernel<16><<<(N + 15) / 16, 256, 0, stream>>>(
        x, W1, b1, W2, b2, Wc, bc, Sxh, S2h, S4h, cnt, out, N);
}

// Round 4
// 1242.225 us; speedup vs baseline: 2.0171x; 1.1352x over previous
//
#include <hip/hip_runtime.h>

constexpr int F  = 128;   // input feature dim
constexpr int H1 = 256;
constexpr int H2 = 128;
constexpr int C  = 40;

using f32x4 = __attribute__((ext_vector_type(4))) float;
using f16x8 = __attribute__((ext_vector_type(8))) _Float16;

__device__ __forceinline__ float wave_sum64(float v) {
#pragma unroll
    for (int off = 32; off > 0; off >>= 1) v += __shfl_xor(v, off, 64);
    return v;
}

// ---------------------------------------------------------------------------
// Weight prep: transpose + fp16-convert W1, W2 into workspace.
// ---------------------------------------------------------------------------
__global__ __launch_bounds__(256) void prep_weights(
    const float* __restrict__ W1, const float* __restrict__ W2,
    _Float16* __restrict__ W1t, _Float16* __restrict__ W2t)
{
    const int i = blockIdx.x * 256 + threadIdx.x;
    if (i < H1 * F) {
        const int j = i >> 7, f = i & 127;
        W1t[i] = (_Float16)W1[(size_t)f * H1 + j];
    }
    if (i < H2 * H1) {
        const int j = i >> 8, k = i & 255;
        W2t[i] = (_Float16)W2[(size_t)k * H2 + j];
    }
}

// ---------------------------------------------------------------------------
// Counting sort of edges by segment: hist -> 3-pass scan -> scatter.
// ---------------------------------------------------------------------------
__global__ __launch_bounds__(256) void k_hist(
    const int* __restrict__ seg, int* __restrict__ hist, int E)
{
    const int e = blockIdx.x * 256 + threadIdx.x;
    if (e < E) atomicAdd(&hist[seg[e]], 1);
}

__global__ __launch_bounds__(256) void k_scan1(
    const int* __restrict__ hist, int* __restrict__ bsum, int N)
{
    __shared__ int s[256];
    const int t = threadIdx.x;
    const int i = blockIdx.x * 256 + t;
    s[t] = (i < N) ? hist[i] : 0;
    __syncthreads();
#pragma unroll
    for (int off = 128; off > 0; off >>= 1) {
        if (t < off) s[t] += s[t + off];
        __syncthreads();
    }
    if (t == 0) bsum[blockIdx.x] = s[0];
}

__global__ __launch_bounds__(256) void k_scan2(int* __restrict__ bsum, int B)
{
    __shared__ int s[256];
    const int t = threadIdx.x;
    const int v = (t < B) ? bsum[t] : 0;
    s[t] = v;
    __syncthreads();
#pragma unroll
    for (int off = 1; off < 256; off <<= 1) {
        const int u = (t >= off) ? s[t - off] : 0;
        __syncthreads();
        s[t] += u;
        __syncthreads();
    }
    if (t < B) bsum[t] = s[t] - v;   // exclusive block offsets
}

__global__ __launch_bounds__(256) void k_scan3(
    const int* __restrict__ hist, const int* __restrict__ bsum,
    int* __restrict__ start, int* __restrict__ cursor, int N, int E)
{
    __shared__ int s[256];
    const int t = threadIdx.x;
    const int i = blockIdx.x * 256 + t;
    const int v = (i < N) ? hist[i] : 0;
    s[t] = v;
    __syncthreads();
#pragma unroll
    for (int off = 1; off < 256; off <<= 1) {
        const int u = (t >= off) ? s[t - off] : 0;
        __syncthreads();
        s[t] += u;
        __syncthreads();
    }
    if (i < N) {
        start[i]  = bsum[blockIdx.x] + s[t] - v;
        cursor[i] = 0;
    }
    if (i == 0) start[N] = E;
}

__global__ __launch_bounds__(256) void k_scatter(
    const int* __restrict__ seg, const int* __restrict__ start,
    int* __restrict__ cursor, int* __restrict__ ord, int E)
{
    const int e = blockIdx.x * 256 + threadIdx.x;
    if (e < E) {
        const int s = seg[e];
        const int r = atomicAdd(&cursor[s], 1);
        ord[start[s] + r] = e;
    }
}

// ---------------------------------------------------------------------------
// Edge kernel v4: 64 SORTED edges/block, 4 waves.
//   Phase A: gather nbx[ord[...]], l2norm -> s_A (f16)
//   agg Sx (runs; store if segment complete in tile, else atomicAdd f32)
//   GEMM1 (MFMA) -> s_nh pre-relu f16
//   agg S2 (relu on read)
//   GEMM2 (MFMA) -> s_A overwritten with n_h2 pre-relu
//   agg S4 (relu on read)
// ---------------------------------------------------------------------------
__global__ __launch_bounds__(256) void edge_kernel4(
    const float* __restrict__ nbx, const int* __restrict__ seg,
    const int* __restrict__ ord, const int* __restrict__ start,
    const _Float16* __restrict__ W1t, const float* __restrict__ b1,
    const _Float16* __restrict__ W2t, const float* __restrict__ b2,
    float* __restrict__ Sx, float* __restrict__ S2, float* __restrict__ S4,
    int E)
{
    __shared__ _Float16 s_A[64][136];    // nb, later n_h2 (pre-relu)
    __shared__ _Float16 s_nh[64][264];   // n_h (pre-relu)
    __shared__ int s_seg[64];
    __shared__ int s_ord[64];
    __shared__ int s_flag[64];

    const int tid  = threadIdx.x;
    const int lane = tid & 63;
    const int w    = tid >> 6;
    const int e0   = blockIdx.x * 64;
    const int mrow = lane & 15;
    const int kgrp = lane >> 4;

    if (tid < 64) {
        const int e    = e0 + tid;
        const int edge = (e < E) ? ord[e] : -1;
        const int sg   = (edge >= 0) ? seg[edge] : -1;
        s_ord[tid] = edge;
        s_seg[tid] = sg;
        int fl = 0;
        if (sg >= 0) fl = (start[sg] >= e0) && (start[sg + 1] <= e0 + 64);
        s_flag[tid] = fl;
    }
    __syncthreads();

    // ---- Phase A: gather + l2norm ----
#pragma unroll 4
    for (int i = 0; i < 16; ++i) {
        const int r = w * 16 + i;
        const int edge = s_ord[r];
        float v0 = 0.f, v1 = 0.f;
        if (edge >= 0) {
            v0 = nbx[(size_t)edge * F + lane];
            v1 = nbx[(size_t)edge * F + 64 + lane];
        }
        const float ss = wave_sum64(v0 * v0 + v1 * v1);
        const float sc = 1.0f / fmaxf(sqrtf(ss), 1e-12f);
        s_A[r][lane]      = (_Float16)(v0 * sc);
        s_A[r][64 + lane] = (_Float16)(v1 * sc);
    }

    // A-fragments for GEMM1 (own rows; written by this wave)
    f16x8 a1[4];
#pragma unroll
    for (int kk = 0; kk < 4; ++kk)
        a1[kk] = *(const f16x8*)&s_A[w * 16 + mrow][kk * 32 + kgrp * 8];

    __syncthreads();   // s_A complete for Sx aggregation

    // ---- Sx aggregation (threads 0..127; col j = tid) ----
    if (tid < 128) {
        const int j = tid;
        float acc = 0.f;
        int cur = s_seg[0];
        int curflag = s_flag[0];
#pragma unroll 1
        for (int r = 1; r <= 64; ++r) {
            acc += (float)s_A[r - 1][j];
            const int nxt = (r < 64) ? s_seg[r] : -2;
            if (nxt != cur) {
                if (cur >= 0) {
                    float* dst = &Sx[(size_t)cur * F + j];
                    if (curflag) *dst = acc; else atomicAdd(dst, acc);
                }
                acc = 0.f;
                cur = nxt;
                curflag = (r < 64) ? s_flag[r] : 0;
            }
        }
    }

    // ---- GEMM1: n_h = A @ W1t^T (M=16/wave, N=256, K=128) ----
#pragma unroll
    for (int n = 0; n < 16; ++n) {
        const int col = n * 16 + mrow;
        f32x4 acc = {0.f, 0.f, 0.f, 0.f};
#pragma unroll
        for (int kk = 0; kk < 4; ++kk) {
            const f16x8 b = *(const f16x8*)&W1t[(size_t)col * F + kk * 32 + kgrp * 8];
            acc = __builtin_amdgcn_mfma_f32_16x16x32_f16(a1[kk], b, acc, 0, 0, 0);
        }
        const float bj = b1[col];
#pragma unroll
        for (int r = 0; r < 4; ++r)
            s_nh[w * 16 + kgrp * 4 + r][col] = (_Float16)(acc[r] + bj);
    }

    // A-fragments for GEMM2 (own rows; written by this wave in GEMM1)
    f16x8 a2[8];
#pragma unroll
    for (int k0 = 0; k0 < 8; ++k0)
        a2[k0] = *(const f16x8*)&s_nh[w * 16 + mrow][k0 * 32 + kgrp * 8];

    __syncthreads();   // s_nh complete; Sx agg done

    // ---- GEMM2: n_h2 = n_h @ W2t^T (M=16/wave, N=128, K=256) -> s_A ----
#pragma unroll
    for (int n = 0; n < 8; ++n) {
        const int col = n * 16 + mrow;
        f32x4 acc = {0.f, 0.f, 0.f, 0.f};
#pragma unroll
        for (int k0 = 0; k0 < 8; ++k0) {
            const f16x8 b = *(const f16x8*)&W2t[(size_t)col * H1 + k0 * 32 + kgrp * 8];
            acc = __builtin_amdgcn_mfma_f32_16x16x32_f16(a2[k0], b, acc, 0, 0, 0);
        }
        const float bj = b2[col];
#pragma unroll
        for (int r = 0; r < 4; ++r)
            s_A[w * 16 + kgrp * 4 + r][col] = (_Float16)(acc[r] + bj);
    }

    // ---- S2 aggregation (all 256 threads; col j = tid; relu on read) ----
    {
        const int j = tid;
        float acc = 0.f;
        int cur = s_seg[0];
        int curflag = s_flag[0];
#pragma unroll 1
        for (int r = 1; r <= 64; ++r) {
            acc += fmaxf((float)s_nh[r - 1][j], 0.f);
            const int nxt = (r < 64) ? s_seg[r] : -2;
            if (nxt != cur) {
                if (cur >= 0) {
                    float* dst = &S2[(size_t)cur * H1 + j];
                    if (curflag) *dst = acc; else atomicAdd(dst, acc);
                }
                acc = 0.f;
                cur = nxt;
                curflag = (r < 64) ? s_flag[r] : 0;
            }
        }
    }

    __syncthreads();   // s_A (n_h2) complete

    // ---- S4 aggregation (threads 0..127; relu on read) ----
    if (tid < 128) {
        const int j = tid;
        float acc = 0.f;
        int cur = s_seg[0];
        int curflag = s_flag[0];
#pragma unroll 1
        for (int r = 1; r <= 64; ++r) {
            acc += fmaxf((float)s_A[r - 1][j], 0.f);
            const int nxt = (r < 64) ? s_seg[r] : -2;
            if (nxt != cur) {
                if (cur >= 0) {
                    float* dst = &S4[(size_t)cur * H2 + j];
                    if (curflag) *dst = acc; else atomicAdd(dst, acc);
                }
                acc = 0.f;
                cur = nxt;
                curflag = (r < 64) ? s_flag[r] : 0;
            }
        }
    }
}

// ---------------------------------------------------------------------------
// Node kernel: full per-node chain in fp32; S buffers fp32; cnt from start[].
// ---------------------------------------------------------------------------
template <int TILE>
__global__ __launch_bounds__(256) void node_kernel(
    const float* __restrict__ x,
    const float* __restrict__ W1, const float* __restrict__ b1,
    const float* __restrict__ W2, const float* __restrict__ b2,
    const float* __restrict__ Wc, const float* __restrict__ bc,
    const float* __restrict__ Sx, const float* __restrict__ S2,
    const float* __restrict__ S4, const int* __restrict__ start,
    float* __restrict__ out, int N)
{
    __shared__ float s_xn[TILE][F];
    __shared__ float s_sx[TILE][F];
    __shared__ float s_x2[TILE][H1];
    __shared__ float s_s1[TILE][H1];
    __shared__ float s_x4[TILE][H2];
    __shared__ float s_cnt[TILE];

    const int tid  = threadIdx.x;
    const int n0   = blockIdx.x * TILE;
    const int wave = tid >> 6;
    const int lane = tid & 63;

#pragma unroll
    for (int r = wave; r < TILE; r += 4) {
        const int n = n0 + r;
        float v0 = 0.f, v1 = 0.f, u0 = 0.f, u1 = 0.f, c = 0.f;
        if (n < N) {
            v0 = x[(size_t)n * F + lane];
            v1 = x[(size_t)n * F + 64 + lane];
            u0 = Sx[(size_t)n * F + lane];
            u1 = Sx[(size_t)n * F + 64 + lane];
            c  = (float)(start[n + 1] - start[n]);
        }
        const float ss = wave_sum64(v0 * v0 + v1 * v1);
        const float sc = 1.0f / fmaxf(sqrtf(ss), 1e-12f);
        s_xn[r][lane]      = v0 * sc;
        s_xn[r][64 + lane] = v1 * sc;
        s_sx[r][lane]      = u0;
        s_sx[r][64 + lane] = u1;
        if (lane == 0) s_cnt[r] = c;
    }
    __syncthreads();

    {
        const int j = tid;
        float ah[TILE], as[TILE];
#pragma unroll
        for (int e = 0; e < TILE; ++e) { ah[e] = 0.f; as[e] = 0.f; }
        for (int f = 0; f < F; f += 4) {
            const float w0 = W1[(size_t)(f + 0) * H1 + j];
            const float w1 = W1[(size_t)(f + 1) * H1 + j];
            const float w2 = W1[(size_t)(f + 2) * H1 + j];
            const float w3 = W1[(size_t)(f + 3) * H1 + j];
#pragma unroll
            for (int e = 0; e < TILE; ++e) {
                const float4 a = *(const float4*)&s_xn[e][f];
                const float4 b = *(const float4*)&s_sx[e][f];
                ah[e] = fmaf(a.x, w0, fmaf(a.y, w1, fmaf(a.z, w2, fmaf(a.w, w3, ah[e]))));
                as[e] = fmaf(b.x, w0, fmaf(b.y, w1, fmaf(b.z, w2, fmaf(b.w, w3, as[e]))));
            }
        }
        const float bj = b1[j];
#pragma unroll
        for (int e = 0; e < TILE; ++e) {
            const int n = n0 + e;
            if (n < N) {
                const float h  = ah[e] + bj;
                const float S1 = as[e] + s_cnt[e] * bj;
                const float x1 = fmaxf(h + 0.9f * S1, 0.f);
                const float x2v = 0.9f * (x1 + S2[(size_t)n * H1 + j]) + 0.1f * h;
                s_x2[e][j] = x2v;
                s_s1[e][j] = S1;
            } else {
                s_x2[e][j] = 0.f;
                s_s1[e][j] = 0.f;
            }
        }
    }
    __syncthreads();

    {
        const int p = tid >> 7;
        const int j = tid & 127;
        float a2[TILE / 2], a3[TILE / 2];
#pragma unroll
        for (int i = 0; i < TILE / 2; ++i) { a2[i] = 0.f; a3[i] = 0.f; }
        for (int k = 0; k < H1; k += 4) {
            const float w0 = W2[(size_t)(k + 0) * H2 + j];
            const float w1 = W2[(size_t)(k + 1) * H2 + j];
            const float w2 = W2[(size_t)(k + 2) * H2 + j];
            const float w3 = W2[(size_t)(k + 3) * H2 + j];
#pragma unroll
            for (int i = 0; i < TILE / 2; ++i) {
                const float4 a = *(const float4*)&s_x2[2 * i + p][k];
                const float4 b = *(const float4*)&s_s1[2 * i + p][k];
                a2[i] = fmaf(a.x, w0, fmaf(a.y, w1, fmaf(a.z, w2, fmaf(a.w, w3, a2[i]))));
                a3[i] = fmaf(b.x, w0, fmaf(b.y, w1, fmaf(b.z, w2, fmaf(b.w, w3, a3[i]))));
            }
        }
        const float bj = b2[j];
#pragma unroll
        for (int i = 0; i < TILE / 2; ++i) {
            const int e = 2 * i + p;
            const int n = n0 + e;
            if (n < N) {
                const float h2 = a2[i] + bj;
                const float S3 = a3[i] + s_cnt[e] * bj;
                const float x3 = fmaxf(h2 + 0.9f * S3, 0.f);
                s_x4[e][j] = 0.9f * (x3 + S4[(size_t)n * H2 + j]) + 0.1f * h2;
            } else {
                s_x4[e][j] = 0.f;
            }
        }
    }
    __syncthreads();

    if (tid < 240) {
        const int g = tid / 40;
        const int c = tid % 40;
        float acc[3] = {0.f, 0.f, 0.f};
        for (int f = 0; f < H2; ++f) {
            const float w = Wc[(size_t)f * C + c];
#pragma unroll
            for (int i = 0; i < 3; ++i) {
                const int r = g + 6 * i;
                if (r < TILE) acc[i] += s_x4[r][f] * w;
            }
        }
        const float bcc = bc[c];
#pragma unroll
        for (int i = 0; i < 3; ++i) {
            const int r = g + 6 * i;
            const int n = n0 + r;
            if (r < TILE && n < N) out[(size_t)n * C + c] = acc[i] + bcc;
        }
    }
}

extern "C" void kernel_launch(void* const* d_in, const int* in_sizes, int n_in,
                              void* d_out, int out_size, void* d_ws, size_t ws_size,
                              hipStream_t stream) {
    const float* x   = (const float*)d_in[0];
    const float* nbx = (const float*)d_in[1];
    const float* W1  = (const float*)d_in[2];
    const float* b1  = (const float*)d_in[3];
    const float* W2  = (const float*)d_in[4];
    const float* b2  = (const float*)d_in[5];
    const float* Wc  = (const float*)d_in[6];
    const float* bc  = (const float*)d_in[7];
    const int*   seg = (const int*)d_in[8];

    const int N = in_sizes[0] / F;   // 50000
    const int E = in_sizes[8];       // 600000
    float* out = (float*)d_out;

    // workspace layout:
    // [Sx f32 N*F | S2 f32 N*H1 | S4 f32 N*H2 | hist N | cursor N | bsum 256]  <- zeroed
    // [start N+1 | ord E | W1t f16 | W2t f16]
    float* Sx    = (float*)d_ws;
    float* S2    = Sx + (size_t)N * F;
    float* S4    = S2 + (size_t)N * H1;
    int*   hist  = (int*)(S4 + (size_t)N * H2);
    int*   cursor= hist + N;
    int*   bsum  = cursor + N;
    int*   start = bsum + 256;
    int*   ord   = start + (N + 1);
    char*  wrest = (char*)(ord + E);
    _Float16* W1t = (_Float16*)(((uintptr_t)wrest + 15) & ~(uintptr_t)15);
    _Float16* W2t = W1t + (size_t)H1 * F;

    const size_t zero_bytes = ((size_t)N * (F + H1 + H2)) * 4 + (size_t)N * 8 + 1024;
    hipMemsetAsync(d_ws, 0, zero_bytes, stream);

    prep_weights<<<128, 256, 0, stream>>>(W1, W2, W1t, W2t);

    const int B = (N + 255) / 256;
    k_hist   <<<(E + 255) / 256, 256, 0, stream>>>(seg, hist, E);
    k_scan1  <<<B, 256, 0, stream>>>(hist, bsum, N);
    k_scan2  <<<1, 256, 0, stream>>>(bsum, B);
    k_scan3  <<<B, 256, 0, stream>>>(hist, bsum, start, cursor, N, E);
    k_scatter<<<(E + 255) / 256, 256, 0, stream>>>(seg, start, cursor, ord, E);

    edge_kernel4<<<(E + 63) / 64, 256, 0, stream>>>(
        nbx, seg, ord, start, W1t, b1, W2t, b2, Sx, S2, S4, E);
    node_kernel<16><<<(N + 15) / 16, 256, 0, stream>>>(
        x, W1, b1, W2, b2, Wc, bc, Sx, S2, S4, start, out, N);
}

// Round 5
// 1204.902 us; speedup vs baseline: 2.0796x; 1.0310x over previous
//
#include <hip/hip_runtime.h>

constexpr int F  = 128;   // input feature dim
constexpr int H1 = 256;
constexpr int H2 = 128;
constexpr int C  = 40;

using f32x4 = __attribute__((ext_vector_type(4))) float;
using f16x8 = __attribute__((ext_vector_type(8))) _Float16;

__device__ __forceinline__ float wave_sum64(float v) {
#pragma unroll
    for (int off = 32; off > 0; off >>= 1) v += __shfl_xor(v, off, 64);
    return v;
}

// ---------------------------------------------------------------------------
// Weight prep: transpose + fp16-convert W1, W2 into workspace.
// ---------------------------------------------------------------------------
__global__ __launch_bounds__(256) void prep_weights(
    const float* __restrict__ W1, const float* __restrict__ W2,
    _Float16* __restrict__ W1t, _Float16* __restrict__ W2t)
{
    const int i = blockIdx.x * 256 + threadIdx.x;
    if (i < H1 * F) {
        const int j = i >> 7, f = i & 127;
        W1t[i] = (_Float16)W1[(size_t)f * H1 + j];
    }
    if (i < H2 * H1) {
        const int j = i >> 8, k = i & 255;
        W2t[i] = (_Float16)W2[(size_t)k * H2 + j];
    }
}

// ---------------------------------------------------------------------------
// Counting sort of edges by segment: hist -> 3-pass scan -> scatter.
// ---------------------------------------------------------------------------
__global__ __launch_bounds__(256) void k_hist(
    const int* __restrict__ seg, int* __restrict__ hist, int E)
{
    const int e = blockIdx.x * 256 + threadIdx.x;
    if (e < E) atomicAdd(&hist[seg[e]], 1);
}

__global__ __launch_bounds__(256) void k_scan1(
    const int* __restrict__ hist, int* __restrict__ bsum, int N)
{
    __shared__ int s[256];
    const int t = threadIdx.x;
    const int i = blockIdx.x * 256 + t;
    s[t] = (i < N) ? hist[i] : 0;
    __syncthreads();
#pragma unroll
    for (int off = 128; off > 0; off >>= 1) {
        if (t < off) s[t] += s[t + off];
        __syncthreads();
    }
    if (t == 0) bsum[blockIdx.x] = s[0];
}

__global__ __launch_bounds__(256) void k_scan2(int* __restrict__ bsum, int B)
{
    __shared__ int s[256];
    const int t = threadIdx.x;
    const int v = (t < B) ? bsum[t] : 0;
    s[t] = v;
    __syncthreads();
#pragma unroll
    for (int off = 1; off < 256; off <<= 1) {
        const int u = (t >= off) ? s[t - off] : 0;
        __syncthreads();
        s[t] += u;
        __syncthreads();
    }
    if (t < B) bsum[t] = s[t] - v;   // exclusive block offsets
}

__global__ __launch_bounds__(256) void k_scan3(
    const int* __restrict__ hist, const int* __restrict__ bsum,
    int* __restrict__ start, int* __restrict__ cursor, int N, int E)
{
    __shared__ int s[256];
    const int t = threadIdx.x;
    const int i = blockIdx.x * 256 + t;
    const int v = (i < N) ? hist[i] : 0;
    s[t] = v;
    __syncthreads();
#pragma unroll
    for (int off = 1; off < 256; off <<= 1) {
        const int u = (t >= off) ? s[t - off] : 0;
        __syncthreads();
        s[t] += u;
        __syncthreads();
    }
    if (i < N) {
        start[i]  = bsum[blockIdx.x] + s[t] - v;
        cursor[i] = 0;
    }
    if (i == 0) start[N] = E;
}

__global__ __launch_bounds__(256) void k_scatter(
    const int* __restrict__ seg, const int* __restrict__ start,
    int* __restrict__ cursor, int* __restrict__ ord, int E)
{
    const int e = blockIdx.x * 256 + threadIdx.x;
    if (e < E) {
        const int s = seg[e];
        const int r = atomicAdd(&cursor[s], 1);
        ord[start[s] + r] = e;
    }
}

// ---------------------------------------------------------------------------
// Segmented-run aggregation over 64 sorted LDS rows, column j per thread.
// Batched 8-row register loads so ds_read latency pipelines.
// ---------------------------------------------------------------------------
template <bool RELU>
__device__ __forceinline__ void seg_agg(
    const _Float16 (*__restrict__ s)[264], int j,
    const int* __restrict__ s_seg, const int* __restrict__ s_flag,
    float* __restrict__ Sdst, int ld)
{
    float acc = 0.f;
    int cur = s_seg[0];
    int curflag = s_flag[0];
#pragma unroll
    for (int r0 = 0; r0 < 64; r0 += 8) {
        float v[8];
#pragma unroll
        for (int i = 0; i < 8; ++i) {
            const float t = (float)s[r0 + i][j];
            v[i] = RELU ? fmaxf(t, 0.f) : t;
        }
#pragma unroll
        for (int i = 0; i < 8; ++i) {
            const int r = r0 + i;
            acc += v[i];
            const int nxt = (r < 63) ? s_seg[r + 1] : -2;
            if (nxt != cur) {                       // wave-uniform branch
                if (cur >= 0) {
                    float* dst = &Sdst[(size_t)cur * ld + j];
                    if (curflag) *dst = acc; else atomicAdd(dst, acc);
                }
                acc = 0.f;
                cur = nxt;
                curflag = (r < 63) ? s_flag[r + 1] : 0;
            }
        }
    }
}

// ---------------------------------------------------------------------------
// Edge kernel v5: 64 SORTED edges/block, 4 waves, single overlaid LDS buffer.
//   s_h holds: nb (cols 0..128) -> n_h (cols 0..256) -> n_h2 (cols 0..128)
// Phases:  A(load+l2norm) | Sx agg + a1 frags | GEMM1 | S2 agg + a2 frags |
//          GEMM2 | S4 agg       (barriers between phases)
// ---------------------------------------------------------------------------
__global__ __launch_bounds__(256, 4) void edge_kernel5(
    const float* __restrict__ nbx, const int* __restrict__ seg,
    const int* __restrict__ ord, const int* __restrict__ start,
    const _Float16* __restrict__ W1t, const float* __restrict__ b1,
    const _Float16* __restrict__ W2t, const float* __restrict__ b2,
    float* __restrict__ Sx, float* __restrict__ S2, float* __restrict__ S4,
    int E)
{
    __shared__ _Float16 s_h[64][264];   // 33.8 KB (row stride 528 B)
    __shared__ int s_seg[64];
    __shared__ int s_ord[64];
    __shared__ int s_flag[64];

    const int tid  = threadIdx.x;
    const int lane = tid & 63;
    const int w    = tid >> 6;
    const int e0   = blockIdx.x * 64;
    const int mrow = lane & 15;
    const int kgrp = lane >> 4;

    if (tid < 64) {
        const int e    = e0 + tid;
        const int edge = (e < E) ? ord[e] : -1;
        const int sg   = (edge >= 0) ? seg[edge] : -1;
        s_ord[tid] = edge;
        s_seg[tid] = sg;
        int fl = 0;
        if (sg >= 0) fl = (start[sg] >= e0) && (start[sg + 1] <= e0 + 64);
        s_flag[tid] = fl;
    }
    __syncthreads();

    // ---- Phase A: gather + l2norm (all 32 loads issued up front) ----
    {
        float va[16][2];
#pragma unroll
        for (int i = 0; i < 16; ++i) {
            const int edge = s_ord[w * 16 + i];
            va[i][0] = 0.f; va[i][1] = 0.f;
            if (edge >= 0) {
                va[i][0] = nbx[(size_t)edge * F + lane];
                va[i][1] = nbx[(size_t)edge * F + 64 + lane];
            }
        }
#pragma unroll
        for (int i = 0; i < 16; ++i) {
            const int r = w * 16 + i;
            const float ss = wave_sum64(va[i][0] * va[i][0] + va[i][1] * va[i][1]);
            const float sc = 1.0f / fmaxf(sqrtf(ss), 1e-12f);
            s_h[r][lane]      = (_Float16)(va[i][0] * sc);
            s_h[r][64 + lane] = (_Float16)(va[i][1] * sc);
        }
    }
    __syncthreads();

    // ---- a1 frags (own rows) + Sx aggregation ----
    f16x8 a1[4];
#pragma unroll
    for (int kk = 0; kk < 4; ++kk)
        a1[kk] = *(const f16x8*)&s_h[w * 16 + mrow][kk * 32 + kgrp * 8];

    if (tid < 128) seg_agg<false>(s_h, tid, s_seg, s_flag, Sx, F);
    __syncthreads();

    // ---- GEMM1: n_h = A @ W1t^T (M=16/wave, N=256, K=128) -> s_h[.][0..256) ----
#pragma unroll
    for (int n = 0; n < 16; ++n) {
        const int col = n * 16 + mrow;
        f32x4 acc = {0.f, 0.f, 0.f, 0.f};
#pragma unroll
        for (int kk = 0; kk < 4; ++kk) {
            const f16x8 b = *(const f16x8*)&W1t[(size_t)col * F + kk * 32 + kgrp * 8];
            acc = __builtin_amdgcn_mfma_f32_16x16x32_f16(a1[kk], b, acc, 0, 0, 0);
        }
        const float bj = b1[col];
#pragma unroll
        for (int r = 0; r < 4; ++r)
            s_h[w * 16 + kgrp * 4 + r][col] = (_Float16)(acc[r] + bj);
    }
    __syncthreads();

    // ---- a2 frags (own rows, written by own wave) + S2 aggregation ----
    f16x8 a2[8];
#pragma unroll
    for (int k0 = 0; k0 < 8; ++k0)
        a2[k0] = *(const f16x8*)&s_h[w * 16 + mrow][k0 * 32 + kgrp * 8];

    seg_agg<true>(s_h, tid, s_seg, s_flag, S2, H1);
    __syncthreads();

    // ---- GEMM2: n_h2 = n_h @ W2t^T (M=16/wave, N=128, K=256) -> s_h[.][0..128) ----
#pragma unroll
    for (int n = 0; n < 8; ++n) {
        const int col = n * 16 + mrow;
        f32x4 acc = {0.f, 0.f, 0.f, 0.f};
#pragma unroll
        for (int k0 = 0; k0 < 8; ++k0) {
            const f16x8 b = *(const f16x8*)&W2t[(size_t)col * H1 + k0 * 32 + kgrp * 8];
            acc = __builtin_amdgcn_mfma_f32_16x16x32_f16(a2[k0], b, acc, 0, 0, 0);
        }
        const float bj = b2[col];
#pragma unroll
        for (int r = 0; r < 4; ++r)
            s_h[w * 16 + kgrp * 4 + r][col] = (_Float16)(acc[r] + bj);
    }
    __syncthreads();

    // ---- S4 aggregation ----
    if (tid < 128) seg_agg<true>(s_h, tid, s_seg, s_flag, S4, H2);
}

// ---------------------------------------------------------------------------
// Node kernel: full per-node chain in fp32; cnt from start[].
// ---------------------------------------------------------------------------
template <int TILE>
__global__ __launch_bounds__(256) void node_kernel(
    const float* __restrict__ x,
    const float* __restrict__ W1, const float* __restrict__ b1,
    const float* __restrict__ W2, const float* __restrict__ b2,
    const float* __restrict__ Wc, const float* __restrict__ bc,
    const float* __restrict__ Sx, const float* __restrict__ S2,
    const float* __restrict__ S4, const int* __restrict__ start,
    float* __restrict__ out, int N)
{
    __shared__ float s_xn[TILE][F];
    __shared__ float s_sx[TILE][F];
    __shared__ float s_x2[TILE][H1];
    __shared__ float s_s1[TILE][H1];
    __shared__ float s_x4[TILE][H2];
    __shared__ float s_cnt[TILE];

    const int tid  = threadIdx.x;
    const int n0   = blockIdx.x * TILE;
    const int wave = tid >> 6;
    const int lane = tid & 63;

#pragma unroll
    for (int r = wave; r < TILE; r += 4) {
        const int n = n0 + r;
        float v0 = 0.f, v1 = 0.f, u0 = 0.f, u1 = 0.f, c = 0.f;
        if (n < N) {
            v0 = x[(size_t)n * F + lane];
            v1 = x[(size_t)n * F + 64 + lane];
            u0 = Sx[(size_t)n * F + lane];
            u1 = Sx[(size_t)n * F + 64 + lane];
            c  = (float)(start[n + 1] - start[n]);
        }
        const float ss = wave_sum64(v0 * v0 + v1 * v1);
        const float sc = 1.0f / fmaxf(sqrtf(ss), 1e-12f);
        s_xn[r][lane]      = v0 * sc;
        s_xn[r][64 + lane] = v1 * sc;
        s_sx[r][lane]      = u0;
        s_sx[r][64 + lane] = u1;
        if (lane == 0) s_cnt[r] = c;
    }
    __syncthreads();

    {
        const int j = tid;
        float ah[TILE], as[TILE];
#pragma unroll
        for (int e = 0; e < TILE; ++e) { ah[e] = 0.f; as[e] = 0.f; }
        for (int f = 0; f < F; f += 4) {
            const float w0 = W1[(size_t)(f + 0) * H1 + j];
            const float w1 = W1[(size_t)(f + 1) * H1 + j];
            const float w2 = W1[(size_t)(f + 2) * H1 + j];
            const float w3 = W1[(size_t)(f + 3) * H1 + j];
#pragma unroll
            for (int e = 0; e < TILE; ++e) {
                const float4 a = *(const float4*)&s_xn[e][f];
                const float4 b = *(const float4*)&s_sx[e][f];
                ah[e] = fmaf(a.x, w0, fmaf(a.y, w1, fmaf(a.z, w2, fmaf(a.w, w3, ah[e]))));
                as[e] = fmaf(b.x, w0, fmaf(b.y, w1, fmaf(b.z, w2, fmaf(b.w, w3, as[e]))));
            }
        }
        const float bj = b1[j];
#pragma unroll
        for (int e = 0; e < TILE; ++e) {
            const int n = n0 + e;
            if (n < N) {
                const float h  = ah[e] + bj;
                const float S1 = as[e] + s_cnt[e] * bj;
                const float x1 = fmaxf(h + 0.9f * S1, 0.f);
                const float x2v = 0.9f * (x1 + S2[(size_t)n * H1 + j]) + 0.1f * h;
                s_x2[e][j] = x2v;
                s_s1[e][j] = S1;
            } else {
                s_x2[e][j] = 0.f;
                s_s1[e][j] = 0.f;
            }
        }
    }
    __syncthreads();

    {
        const int p = tid >> 7;
        const int j = tid & 127;
        float a2[TILE / 2], a3[TILE / 2];
#pragma unroll
        for (int i = 0; i < TILE / 2; ++i) { a2[i] = 0.f; a3[i] = 0.f; }
        for (int k = 0; k < H1; k += 4) {
            const float w0 = W2[(size_t)(k + 0) * H2 + j];
            const float w1 = W2[(size_t)(k + 1) * H2 + j];
            const float w2 = W2[(size_t)(k + 2) * H2 + j];
            const float w3 = W2[(size_t)(k + 3) * H2 + j];
#pragma unroll
            for (int i = 0; i < TILE / 2; ++i) {
                const float4 a = *(const float4*)&s_x2[2 * i + p][k];
                const float4 b = *(const float4*)&s_s1[2 * i + p][k];
                a2[i] = fmaf(a.x, w0, fmaf(a.y, w1, fmaf(a.z, w2, fmaf(a.w, w3, a2[i]))));
                a3[i] = fmaf(b.x, w0, fmaf(b.y, w1, fmaf(b.z, w2, fmaf(b.w, w3, a3[i]))));
            }
        }
        const float bj = b2[j];
#pragma unroll
        for (int i = 0; i < TILE / 2; ++i) {
            const int e = 2 * i + p;
            const int n = n0 + e;
            if (n < N) {
                const float h2 = a2[i] + bj;
                const float S3 = a3[i] + s_cnt[e] * bj;
                const float x3 = fmaxf(h2 + 0.9f * S3, 0.f);
                s_x4[e][j] = 0.9f * (x3 + S4[(size_t)n * H2 + j]) + 0.1f * h2;
            } else {
                s_x4[e][j] = 0.f;
            }
        }
    }
    __syncthreads();

    if (tid < 240) {
        const int g = tid / 40;
        const int c = tid % 40;
        float acc[3] = {0.f, 0.f, 0.f};
        for (int f = 0; f < H2; ++f) {
            const float w = Wc[(size_t)f * C + c];
#pragma unroll
            for (int i = 0; i < 3; ++i) {
                const int r = g + 6 * i;
                if (r < TILE) acc[i] += s_x4[r][f] * w;
            }
        }
        const float bcc = bc[c];
#pragma unroll
        for (int i = 0; i < 3; ++i) {
            const int r = g + 6 * i;
            const int n = n0 + r;
            if (r < TILE && n < N) out[(size_t)n * C + c] = acc[i] + bcc;
        }
    }
}

extern "C" void kernel_launch(void* const* d_in, const int* in_sizes, int n_in,
                              void* d_out, int out_size, void* d_ws, size_t ws_size,
                              hipStream_t stream) {
    const float* x   = (const float*)d_in[0];
    const float* nbx = (const float*)d_in[1];
    const float* W1  = (const float*)d_in[2];
    const float* b1  = (const float*)d_in[3];
    const float* W2  = (const float*)d_in[4];
    const float* b2  = (const float*)d_in[5];
    const float* Wc  = (const float*)d_in[6];
    const float* bc  = (const float*)d_in[7];
    const int*   seg = (const int*)d_in[8];

    const int N = in_sizes[0] / F;   // 50000
    const int E = in_sizes[8];       // 600000
    float* out = (float*)d_out;

    // workspace layout:
    // [Sx f32 N*F | S2 f32 N*H1 | S4 f32 N*H2 | hist N | cursor N | bsum 256] <- zeroed
    // [start N+1 | ord E | W1t f16 | W2t f16]
    float* Sx    = (float*)d_ws;
    float* S2    = Sx + (size_t)N * F;
    float* S4    = S2 + (size_t)N * H1;
    int*   hist  = (int*)(S4 + (size_t)N * H2);
    int*   cursor= hist + N;
    int*   bsum  = cursor + N;
    int*   start = bsum + 256;
    int*   ord   = start + (N + 1);
    char*  wrest = (char*)(ord + E);
    _Float16* W1t = (_Float16*)(((uintptr_t)wrest + 15) & ~(uintptr_t)15);
    _Float16* W2t = W1t + (size_t)H1 * F;

    const size_t zero_bytes = ((size_t)N * (F + H1 + H2)) * 4 + (size_t)N * 8 + 1024;
    hipMemsetAsync(d_ws, 0, zero_bytes, stream);

    prep_weights<<<128, 256, 0, stream>>>(W1, W2, W1t, W2t);

    const int B = (N + 255) / 256;
    k_hist   <<<(E + 255) / 256, 256, 0, stream>>>(seg, hist, E);
    k_scan1  <<<B, 256, 0, stream>>>(hist, bsum, N);
    k_scan2  <<<1, 256, 0, stream>>>(bsum, B);
    k_scan3  <<<B, 256, 0, stream>>>(hist, bsum, start, cursor, N, E);
    k_scatter<<<(E + 255) / 256, 256, 0, stream>>>(seg, start, cursor, ord, E);

    edge_kernel5<<<(E + 63) / 64, 256, 0, stream>>>(
        nbx, seg, ord, start, W1t, b1, W2t, b2, Sx, S2, S4, E);
    node_kernel<16><<<(N + 15) / 16, 256, 0, stream>>>(
        x, W1, b1, W2, b2, Wc, bc, Sx, S2, S4, start, out, N);
}

// Round 6
// 1191.713 us; speedup vs baseline: 2.1026x; 1.0111x over previous
//
#include <hip/hip_runtime.h>

constexpr int F  = 128;   // input feature dim
constexpr int H1 = 256;
constexpr int H2 = 128;
constexpr int C  = 40;

using f32x4 = __attribute__((ext_vector_type(4))) float;
using f16x8 = __attribute__((ext_vector_type(8))) _Float16;
using f16x2 = __attribute__((ext_vector_type(2))) _Float16;

__device__ __forceinline__ float wave_sum64(float v) {
#pragma unroll
    for (int off = 32; off > 0; off >>= 1) v += __shfl_xor(v, off, 64);
    return v;
}

// ---------------------------------------------------------------------------
// Weight prep: transpose + fp16-convert W1, W2 into workspace.
// ---------------------------------------------------------------------------
__global__ __launch_bounds__(256) void prep_weights(
    const float* __restrict__ W1, const float* __restrict__ W2,
    _Float16* __restrict__ W1t, _Float16* __restrict__ W2t)
{
    const int i = blockIdx.x * 256 + threadIdx.x;
    if (i < H1 * F) {
        const int j = i >> 7, f = i & 127;
        W1t[i] = (_Float16)W1[(size_t)f * H1 + j];
    }
    if (i < H2 * H1) {
        const int j = i >> 8, k = i & 255;
        W2t[i] = (_Float16)W2[(size_t)k * H2 + j];
    }
}

// ---------------------------------------------------------------------------
// Counting sort of edges by segment: hist -> 3-pass scan -> scatter.
// ---------------------------------------------------------------------------
__global__ __launch_bounds__(256) void k_hist(
    const int* __restrict__ seg, int* __restrict__ hist, int E)
{
    const int e = blockIdx.x * 256 + threadIdx.x;
    if (e < E) atomicAdd(&hist[seg[e]], 1);
}

__global__ __launch_bounds__(256) void k_scan1(
    const int* __restrict__ hist, int* __restrict__ bsum, int N)
{
    __shared__ int s[256];
    const int t = threadIdx.x;
    const int i = blockIdx.x * 256 + t;
    s[t] = (i < N) ? hist[i] : 0;
    __syncthreads();
#pragma unroll
    for (int off = 128; off > 0; off >>= 1) {
        if (t < off) s[t] += s[t + off];
        __syncthreads();
    }
    if (t == 0) bsum[blockIdx.x] = s[0];
}

__global__ __launch_bounds__(256) void k_scan2(int* __restrict__ bsum, int B)
{
    __shared__ int s[256];
    const int t = threadIdx.x;
    const int v = (t < B) ? bsum[t] : 0;
    s[t] = v;
    __syncthreads();
#pragma unroll
    for (int off = 1; off < 256; off <<= 1) {
        const int u = (t >= off) ? s[t - off] : 0;
        __syncthreads();
        s[t] += u;
        __syncthreads();
    }
    if (t < B) bsum[t] = s[t] - v;   // exclusive block offsets
}

__global__ __launch_bounds__(256) void k_scan3(
    const int* __restrict__ hist, const int* __restrict__ bsum,
    int* __restrict__ start, int* __restrict__ cursor, int N, int E)
{
    __shared__ int s[256];
    const int t = threadIdx.x;
    const int i = blockIdx.x * 256 + t;
    const int v = (i < N) ? hist[i] : 0;
    s[t] = v;
    __syncthreads();
#pragma unroll
    for (int off = 1; off < 256; off <<= 1) {
        const int u = (t >= off) ? s[t - off] : 0;
        __syncthreads();
        s[t] += u;
        __syncthreads();
    }
    if (i < N) {
        start[i]  = bsum[blockIdx.x] + s[t] - v;
        cursor[i] = 0;
    }
    if (i == 0) start[N] = E;
}

__global__ __launch_bounds__(256) void k_scatter(
    const int* __restrict__ seg, const int* __restrict__ start,
    int* __restrict__ cursor, int* __restrict__ ord, int E)
{
    const int e = blockIdx.x * 256 + threadIdx.x;
    if (e < E) {
        const int s = seg[e];
        const int r = atomicAdd(&cursor[s], 1);
        ord[start[s] + r] = e;
    }
}

// ---------------------------------------------------------------------------
// Edge kernel v6: ZERO BARRIERS. Each wave owns a private 16-row sorted
// window end-to-end:
//   gather+l2norm (regs) -> Sx agg (REGISTERS) -> f16 rows to private LDS ->
//   GEMM1 (MFMA) -> n_h C-frags to LDS -> S2 agg (f16x2 col pairs) ->
//   a2 frags -> GEMM2 -> n_h2 C-frags to LDS -> S4 agg
// Run-boundary detection via __shfl(sv, r) with unroll-const r (SALU).
// Complete-in-window segments: plain stores; window-crossing: f32 atomicAdd.
// ---------------------------------------------------------------------------
__global__ __launch_bounds__(256, 4) void edge_kernel6(
    const float* __restrict__ nbx, const int* __restrict__ seg,
    const int* __restrict__ ord, const int* __restrict__ start,
    const _Float16* __restrict__ W1t, const float* __restrict__ b1,
    const _Float16* __restrict__ W2t, const float* __restrict__ b2,
    float* __restrict__ Sx, float* __restrict__ S2, float* __restrict__ S4,
    int E)
{
    __shared__ _Float16 s_h[4][16][264];   // 33.8 KB, per-wave private

    const int tid   = threadIdx.x;
    const int lane  = tid & 63;
    const int w     = tid >> 6;
    const int wbase = blockIdx.x * 64 + w * 16;   // sorted-index window start
    const int mrow  = lane & 15;
    const int kgrp  = lane >> 4;

    // per-lane (lane&15) row metadata
    const int  p    = wbase + mrow;
    const bool pin  = (p < E);
    const int  edge = pin ? ord[p] : 0;

    // ---- gather 16 rows (32 loads in flight) ----
    float va[16][2];
#pragma unroll
    for (int r = 0; r < 16; ++r) {
        const int er = __shfl(edge, r);
        const bool v = (wbase + r < E);
        va[r][0] = v ? nbx[(size_t)er * F + lane] : 0.f;
        va[r][1] = v ? nbx[(size_t)er * F + 64 + lane] : 0.f;
    }

    const int sv = pin ? seg[edge] : -1;
    int fl = 0;
    if (pin) {
        const int s0 = start[sv], s1 = start[sv + 1];
        fl = (s0 >= wbase) && (s1 <= wbase + 16);
    }

    // ---- l2norm; f16 rows into private LDS; normalized values stay in regs ----
#pragma unroll
    for (int r = 0; r < 16; ++r) {
        const float ss = wave_sum64(va[r][0] * va[r][0] + va[r][1] * va[r][1]);
        const float sc = 1.0f / fmaxf(sqrtf(ss), 1e-12f);
        va[r][0] *= sc; va[r][1] *= sc;
        s_h[w][r][lane]      = (_Float16)va[r][0];
        s_h[w][r][64 + lane] = (_Float16)va[r][1];
    }

    // ---- Sx aggregation from REGISTERS (cols lane, 64+lane) ----
    {
        float a0 = 0.f, a1v = 0.f;
        int cur = __shfl(sv, 0);
        int cf  = __shfl(fl, 0);
#pragma unroll
        for (int r = 0; r < 16; ++r) {
            a0 += va[r][0]; a1v += va[r][1];
            const int nxt = (r < 15) ? __shfl(sv, r + 1) : -2;
            if (nxt != cur) {
                if (cur >= 0) {
                    float* d = &Sx[(size_t)cur * F + lane];
                    if (cf) { d[0] = a0; d[64] = a1v; }
                    else    { atomicAdd(d, a0); atomicAdd(d + 64, a1v); }
                }
                a0 = 0.f; a1v = 0.f; cur = nxt;
                if (r < 15) cf = __shfl(fl, r + 1);
            }
        }
    }

    // ---- a1 fragments from own LDS writes ----
    asm volatile("s_waitcnt lgkmcnt(0)" ::: "memory");
    __builtin_amdgcn_sched_barrier(0);
    f16x8 a1[4];
#pragma unroll
    for (int kk = 0; kk < 4; ++kk)
        a1[kk] = *(const f16x8*)&s_h[w][mrow][kk * 32 + kgrp * 8];

    // ---- GEMM1: n_h = A @ W1t^T (M=16, N=256, K=128); C-frags -> LDS ----
#pragma unroll
    for (int n = 0; n < 16; ++n) {
        const int col = n * 16 + mrow;
        f32x4 acc = {0.f, 0.f, 0.f, 0.f};
#pragma unroll
        for (int kk = 0; kk < 4; ++kk) {
            const f16x8 b = *(const f16x8*)&W1t[(size_t)col * F + kk * 32 + kgrp * 8];
            acc = __builtin_amdgcn_mfma_f32_16x16x32_f16(a1[kk], b, acc, 0, 0, 0);
        }
        const float bj = b1[col];
#pragma unroll
        for (int r = 0; r < 4; ++r)
            s_h[w][kgrp * 4 + r][col] = (_Float16)(acc[r] + bj);
    }

    asm volatile("s_waitcnt lgkmcnt(0)" ::: "memory");
    __builtin_amdgcn_sched_barrier(0);

    // ---- S2 aggregation: col pairs (2*lane, 2*lane+1), 2 halves; relu ----
#pragma unroll
    for (int half = 0; half < 2; ++half) {
        const int c0 = half * 128 + 2 * lane;
        float a0 = 0.f, a1v = 0.f;
        int cur = __shfl(sv, 0);
        int cf  = __shfl(fl, 0);
#pragma unroll
        for (int r = 0; r < 16; ++r) {
            const f16x2 pv = *(const f16x2*)&s_h[w][r][c0];
            a0  += fmaxf((float)pv[0], 0.f);
            a1v += fmaxf((float)pv[1], 0.f);
            const int nxt = (r < 15) ? __shfl(sv, r + 1) : -2;
            if (nxt != cur) {
                if (cur >= 0) {
                    float* d = &S2[(size_t)cur * H1 + c0];
                    if (cf) { *(float2*)d = make_float2(a0, a1v); }
                    else    { atomicAdd(d, a0); atomicAdd(d + 1, a1v); }
                }
                a0 = 0.f; a1v = 0.f; cur = nxt;
                if (r < 15) cf = __shfl(fl, r + 1);
            }
        }
    }

    // ---- a2 fragments ----
    f16x8 a2[8];
#pragma unroll
    for (int k0 = 0; k0 < 8; ++k0)
        a2[k0] = *(const f16x8*)&s_h[w][mrow][k0 * 32 + kgrp * 8];

    // ---- GEMM2: n_h2 = n_h @ W2t^T (M=16, N=128, K=256); C-frags -> LDS ----
#pragma unroll
    for (int n = 0; n < 8; ++n) {
        const int col = n * 16 + mrow;
        f32x4 acc = {0.f, 0.f, 0.f, 0.f};
#pragma unroll
        for (int k0 = 0; k0 < 8; ++k0) {
            const f16x8 b = *(const f16x8*)&W2t[(size_t)col * H1 + k0 * 32 + kgrp * 8];
            acc = __builtin_amdgcn_mfma_f32_16x16x32_f16(a2[k0], b, acc, 0, 0, 0);
        }
        const float bj = b2[col];
#pragma unroll
        for (int r = 0; r < 4; ++r)
            s_h[w][kgrp * 4 + r][col] = (_Float16)(acc[r] + bj);
    }

    asm volatile("s_waitcnt lgkmcnt(0)" ::: "memory");
    __builtin_amdgcn_sched_barrier(0);

    // ---- S4 aggregation: col pairs, single half; relu ----
    {
        const int c0 = 2 * lane;
        float a0 = 0.f, a1v = 0.f;
        int cur = __shfl(sv, 0);
        int cf  = __shfl(fl, 0);
#pragma unroll
        for (int r = 0; r < 16; ++r) {
            const f16x2 pv = *(const f16x2*)&s_h[w][r][c0];
            a0  += fmaxf((float)pv[0], 0.f);
            a1v += fmaxf((float)pv[1], 0.f);
            const int nxt = (r < 15) ? __shfl(sv, r + 1) : -2;
            if (nxt != cur) {
                if (cur >= 0) {
                    float* d = &S4[(size_t)cur * H2 + c0];
                    if (cf) { *(float2*)d = make_float2(a0, a1v); }
                    else    { atomicAdd(d, a0); atomicAdd(d + 1, a1v); }
                }
                a0 = 0.f; a1v = 0.f; cur = nxt;
                if (r < 15) cf = __shfl(fl, r + 1);
            }
        }
    }
}

// ---------------------------------------------------------------------------
// Node kernel: full per-node chain in fp32; cnt from start[].
// ---------------------------------------------------------------------------
template <int TILE>
__global__ __launch_bounds__(256) void node_kernel(
    const float* __restrict__ x,
    const float* __restrict__ W1, const float* __restrict__ b1,
    const float* __restrict__ W2, const float* __restrict__ b2,
    const float* __restrict__ Wc, const float* __restrict__ bc,
    const float* __restrict__ Sx, const float* __restrict__ S2,
    const float* __restrict__ S4, const int* __restrict__ start,
    float* __restrict__ out, int N)
{
    __shared__ float s_xn[TILE][F];
    __shared__ float s_sx[TILE][F];
    __shared__ float s_x2[TILE][H1];
    __shared__ float s_s1[TILE][H1];
    __shared__ float s_x4[TILE][H2];
    __shared__ float s_cnt[TILE];

    const int tid  = threadIdx.x;
    const int n0   = blockIdx.x * TILE;
    const int wave = tid >> 6;
    const int lane = tid & 63;

#pragma unroll
    for (int r = wave; r < TILE; r += 4) {
        const int n = n0 + r;
        float v0 = 0.f, v1 = 0.f, u0 = 0.f, u1 = 0.f, c = 0.f;
        if (n < N) {
            v0 = x[(size_t)n * F + lane];
            v1 = x[(size_t)n * F + 64 + lane];
            u0 = Sx[(size_t)n * F + lane];
            u1 = Sx[(size_t)n * F + 64 + lane];
            c  = (float)(start[n + 1] - start[n]);
        }
        const float ss = wave_sum64(v0 * v0 + v1 * v1);
        const float sc = 1.0f / fmaxf(sqrtf(ss), 1e-12f);
        s_xn[r][lane]      = v0 * sc;
        s_xn[r][64 + lane] = v1 * sc;
        s_sx[r][lane]      = u0;
        s_sx[r][64 + lane] = u1;
        if (lane == 0) s_cnt[r] = c;
    }
    __syncthreads();

    {
        const int j = tid;
        float ah[TILE], as[TILE];
#pragma unroll
        for (int e = 0; e < TILE; ++e) { ah[e] = 0.f; as[e] = 0.f; }
        for (int f = 0; f < F; f += 4) {
            const float w0 = W1[(size_t)(f + 0) * H1 + j];
            const float w1 = W1[(size_t)(f + 1) * H1 + j];
            const float w2 = W1[(size_t)(f + 2) * H1 + j];
            const float w3 = W1[(size_t)(f + 3) * H1 + j];
#pragma unroll
            for (int e = 0; e < TILE; ++e) {
                const float4 a = *(const float4*)&s_xn[e][f];
                const float4 b = *(const float4*)&s_sx[e][f];
                ah[e] = fmaf(a.x, w0, fmaf(a.y, w1, fmaf(a.z, w2, fmaf(a.w, w3, ah[e]))));
                as[e] = fmaf(b.x, w0, fmaf(b.y, w1, fmaf(b.z, w2, fmaf(b.w, w3, as[e]))));
            }
        }
        const float bj = b1[j];
#pragma unroll
        for (int e = 0; e < TILE; ++e) {
            const int n = n0 + e;
            if (n < N) {
                const float h  = ah[e] + bj;
                const float S1 = as[e] + s_cnt[e] * bj;
                const float x1 = fmaxf(h + 0.9f * S1, 0.f);
                const float x2v = 0.9f * (x1 + S2[(size_t)n * H1 + j]) + 0.1f * h;
                s_x2[e][j] = x2v;
                s_s1[e][j] = S1;
            } else {
                s_x2[e][j] = 0.f;
                s_s1[e][j] = 0.f;
            }
        }
    }
    __syncthreads();

    {
        const int p = tid >> 7;
        const int j = tid & 127;
        float a2[TILE / 2], a3[TILE / 2];
#pragma unroll
        for (int i = 0; i < TILE / 2; ++i) { a2[i] = 0.f; a3[i] = 0.f; }
        for (int k = 0; k < H1; k += 4) {
            const float w0 = W2[(size_t)(k + 0) * H2 + j];
            const float w1 = W2[(size_t)(k + 1) * H2 + j];
            const float w2 = W2[(size_t)(k + 2) * H2 + j];
            const float w3 = W2[(size_t)(k + 3) * H2 + j];
#pragma unroll
            for (int i = 0; i < TILE / 2; ++i) {
                const float4 a = *(const float4*)&s_x2[2 * i + p][k];
                const float4 b = *(const float4*)&s_s1[2 * i + p][k];
                a2[i] = fmaf(a.x, w0, fmaf(a.y, w1, fmaf(a.z, w2, fmaf(a.w, w3, a2[i]))));
                a3[i] = fmaf(b.x, w0, fmaf(b.y, w1, fmaf(b.z, w2, fmaf(b.w, w3, a3[i]))));
            }
        }
        const float bj = b2[j];
#pragma unroll
        for (int i = 0; i < TILE / 2; ++i) {
            const int e = 2 * i + p;
            const int n = n0 + e;
            if (n < N) {
                const float h2 = a2[i] + bj;
                const float S3 = a3[i] + s_cnt[e] * bj;
                const float x3 = fmaxf(h2 + 0.9f * S3, 0.f);
                s_x4[e][j] = 0.9f * (x3 + S4[(size_t)n * H2 + j]) + 0.1f * h2;
            } else {
                s_x4[e][j] = 0.f;
            }
        }
    }
    __syncthreads();

    if (tid < 240) {
        const int g = tid / 40;
        const int c = tid % 40;
        float acc[3] = {0.f, 0.f, 0.f};
        for (int f = 0; f < H2; ++f) {
            const float w = Wc[(size_t)f * C + c];
#pragma unroll
            for (int i = 0; i < 3; ++i) {
                const int r = g + 6 * i;
                if (r < TILE) acc[i] += s_x4[r][f] * w;
            }
        }
        const float bcc = bc[c];
#pragma unroll
        for (int i = 0; i < 3; ++i) {
            const int r = g + 6 * i;
            const int n = n0 + r;
            if (r < TILE && n < N) out[(size_t)n * C + c] = acc[i] + bcc;
        }
    }
}

extern "C" void kernel_launch(void* const* d_in, const int* in_sizes, int n_in,
                              void* d_out, int out_size, void* d_ws, size_t ws_size,
                              hipStream_t stream) {
    const float* x   = (const float*)d_in[0];
    const float* nbx = (const float*)d_in[1];
    const float* W1  = (const float*)d_in[2];
    const float* b1  = (const float*)d_in[3];
    const float* W2  = (const float*)d_in[4];
    const float* b2  = (const float*)d_in[5];
    const float* Wc  = (const float*)d_in[6];
    const float* bc  = (const float*)d_in[7];
    const int*   seg = (const int*)d_in[8];

    const int N = in_sizes[0] / F;   // 50000
    const int E = in_sizes[8];       // 600000
    float* out = (float*)d_out;

    // workspace layout:
    // [Sx f32 N*F | S2 f32 N*H1 | S4 f32 N*H2 | hist N | cursor N | bsum 256] <- zeroed
    // [start N+1 | ord E | W1t f16 | W2t f16]
    float* Sx    = (float*)d_ws;
    float* S2    = Sx + (size_t)N * F;
    float* S4    = S2 + (size_t)N * H1;
    int*   hist  = (int*)(S4 + (size_t)N * H2);
    int*   cursor= hist + N;
    int*   bsum  = cursor + N;
    int*   start = bsum + 256;
    int*   ord   = start + (N + 1);
    char*  wrest = (char*)(ord + E);
    _Float16* W1t = (_Float16*)(((uintptr_t)wrest + 15) & ~(uintptr_t)15);
    _Float16* W2t = W1t + (size_t)H1 * F;

    const size_t zero_bytes = ((size_t)N * (F + H1 + H2)) * 4 + (size_t)N * 8 + 1024;
    hipMemsetAsync(d_ws, 0, zero_bytes, stream);

    prep_weights<<<128, 256, 0, stream>>>(W1, W2, W1t, W2t);

    const int B = (N + 255) / 256;
    k_hist   <<<(E + 255) / 256, 256, 0, stream>>>(seg, hist, E);
    k_scan1  <<<B, 256, 0, stream>>>(hist, bsum, N);
    k_scan2  <<<1, 256, 0, stream>>>(bsum, B);
    k_scan3  <<<B, 256, 0, stream>>>(hist, bsum, start, cursor, N, E);
    k_scatter<<<(E + 255) / 256, 256, 0, stream>>>(seg, start, cursor, ord, E);

    edge_kernel6<<<(E + 63) / 64, 256, 0, stream>>>(
        nbx, seg, ord, start, W1t, b1, W2t, b2, Sx, S2, S4, E);
    node_kernel<16><<<(N + 15) / 16, 256, 0, stream>>>(
        x, W1, b1, W2, b2, Wc, bc, Sx, S2, S4, start, out, N);
}

// Round 7
// 866.747 us; speedup vs baseline: 2.8910x; 1.3749x over previous
//
#include <hip/hip_runtime.h>

constexpr int F  = 128;   // input feature dim
constexpr int H1 = 256;
constexpr int H2 = 128;
constexpr int C  = 40;

using f32x4 = __attribute__((ext_vector_type(4))) float;
using f16x8 = __attribute__((ext_vector_type(8))) _Float16;
using f16x2 = __attribute__((ext_vector_type(2))) _Float16;

__device__ __forceinline__ float wave_sum64(float v) {
#pragma unroll
    for (int off = 32; off > 0; off >>= 1) v += __shfl_xor(v, off, 64);
    return v;
}

// ---------------------------------------------------------------------------
// Weight prep: transpose + fp16-convert W1, W2, Wc into workspace.
//   W1t[j][f] = W1[f][j]   (256 x 128)
//   W2t[j][k] = W2[k][j]   (128 x 256)
//   Wct[c][k] = Wc[k][c]   (48 x 128, cols >= 40 zero-padded)
// ---------------------------------------------------------------------------
__global__ __launch_bounds__(256) void prep_weights(
    const float* __restrict__ W1, const float* __restrict__ W2,
    const float* __restrict__ Wc,
    _Float16* __restrict__ W1t, _Float16* __restrict__ W2t,
    _Float16* __restrict__ Wct)
{
    const int i = blockIdx.x * 256 + threadIdx.x;
    if (i < H1 * F) {
        const int j = i >> 7, f = i & 127;
        W1t[i] = (_Float16)W1[(size_t)f * H1 + j];
    }
    if (i < H2 * H1) {
        const int j = i >> 8, k = i & 255;
        W2t[i] = (_Float16)W2[(size_t)k * H2 + j];
    }
    if (i < 48 * F) {
        const int c = i >> 7, k = i & 127;
        Wct[i] = (c < C) ? (_Float16)Wc[(size_t)k * C + c] : (_Float16)0.f;
    }
}

// ---------------------------------------------------------------------------
// Counting sort of edges by segment: hist -> 3-pass scan -> scatter.
// ---------------------------------------------------------------------------
__global__ __launch_bounds__(256) void k_hist(
    const int* __restrict__ seg, int* __restrict__ hist, int E)
{
    const int e = blockIdx.x * 256 + threadIdx.x;
    if (e < E) atomicAdd(&hist[seg[e]], 1);
}

__global__ __launch_bounds__(256) void k_scan1(
    const int* __restrict__ hist, int* __restrict__ bsum, int N)
{
    __shared__ int s[256];
    const int t = threadIdx.x;
    const int i = blockIdx.x * 256 + t;
    s[t] = (i < N) ? hist[i] : 0;
    __syncthreads();
#pragma unroll
    for (int off = 128; off > 0; off >>= 1) {
        if (t < off) s[t] += s[t + off];
        __syncthreads();
    }
    if (t == 0) bsum[blockIdx.x] = s[0];
}

__global__ __launch_bounds__(256) void k_scan2(int* __restrict__ bsum, int B)
{
    __shared__ int s[256];
    const int t = threadIdx.x;
    const int v = (t < B) ? bsum[t] : 0;
    s[t] = v;
    __syncthreads();
#pragma unroll
    for (int off = 1; off < 256; off <<= 1) {
        const int u = (t >= off) ? s[t - off] : 0;
        __syncthreads();
        s[t] += u;
        __syncthreads();
    }
    if (t < B) bsum[t] = s[t] - v;   // exclusive block offsets
}

__global__ __launch_bounds__(256) void k_scan3(
    const int* __restrict__ hist, const int* __restrict__ bsum,
    int* __restrict__ start, int* __restrict__ cursor, int N, int E)
{
    __shared__ int s[256];
    const int t = threadIdx.x;
    const int i = blockIdx.x * 256 + t;
    const int v = (i < N) ? hist[i] : 0;
    s[t] = v;
    __syncthreads();
#pragma unroll
    for (int off = 1; off < 256; off <<= 1) {
        const int u = (t >= off) ? s[t - off] : 0;
        __syncthreads();
        s[t] += u;
        __syncthreads();
    }
    if (i < N) {
        start[i]  = bsum[blockIdx.x] + s[t] - v;
        cursor[i] = 0;
    }
    if (i == 0) start[N] = E;
}

__global__ __launch_bounds__(256) void k_scatter(
    const int* __restrict__ seg, const int* __restrict__ start,
    int* __restrict__ cursor, int* __restrict__ ord, int E)
{
    const int e = blockIdx.x * 256 + threadIdx.x;
    if (e < E) {
        const int s = seg[e];
        const int r = atomicAdd(&cursor[s], 1);
        ord[start[s] + r] = e;
    }
}

// ---------------------------------------------------------------------------
// Edge kernel v6 (unchanged from round 6): zero barriers, per-wave 16-row
// sorted windows, register Sx agg, MFMA GEMMs, f16x2 S2/S4 agg.
// ---------------------------------------------------------------------------
__global__ __launch_bounds__(256, 4) void edge_kernel6(
    const float* __restrict__ nbx, const int* __restrict__ seg,
    const int* __restrict__ ord, const int* __restrict__ start,
    const _Float16* __restrict__ W1t, const float* __restrict__ b1,
    const _Float16* __restrict__ W2t, const float* __restrict__ b2,
    float* __restrict__ Sx, float* __restrict__ S2, float* __restrict__ S4,
    int E)
{
    __shared__ _Float16 s_h[4][16][264];   // 33.8 KB, per-wave private

    const int tid   = threadIdx.x;
    const int lane  = tid & 63;
    const int w     = tid >> 6;
    const int wbase = blockIdx.x * 64 + w * 16;
    const int mrow  = lane & 15;
    const int kgrp  = lane >> 4;

    const int  p    = wbase + mrow;
    const bool pin  = (p < E);
    const int  edge = pin ? ord[p] : 0;

    float va[16][2];
#pragma unroll
    for (int r = 0; r < 16; ++r) {
        const int er = __shfl(edge, r);
        const bool v = (wbase + r < E);
        va[r][0] = v ? nbx[(size_t)er * F + lane] : 0.f;
        va[r][1] = v ? nbx[(size_t)er * F + 64 + lane] : 0.f;
    }

    const int sv = pin ? seg[edge] : -1;
    int fl = 0;
    if (pin) {
        const int s0 = start[sv], s1 = start[sv + 1];
        fl = (s0 >= wbase) && (s1 <= wbase + 16);
    }

#pragma unroll
    for (int r = 0; r < 16; ++r) {
        const float ss = wave_sum64(va[r][0] * va[r][0] + va[r][1] * va[r][1]);
        const float sc = 1.0f / fmaxf(sqrtf(ss), 1e-12f);
        va[r][0] *= sc; va[r][1] *= sc;
        s_h[w][r][lane]      = (_Float16)va[r][0];
        s_h[w][r][64 + lane] = (_Float16)va[r][1];
    }

    {
        float a0 = 0.f, a1v = 0.f;
        int cur = __shfl(sv, 0);
        int cf  = __shfl(fl, 0);
#pragma unroll
        for (int r = 0; r < 16; ++r) {
            a0 += va[r][0]; a1v += va[r][1];
            const int nxt = (r < 15) ? __shfl(sv, r + 1) : -2;
            if (nxt != cur) {
                if (cur >= 0) {
                    float* d = &Sx[(size_t)cur * F + lane];
                    if (cf) { d[0] = a0; d[64] = a1v; }
                    else    { atomicAdd(d, a0); atomicAdd(d + 64, a1v); }
                }
                a0 = 0.f; a1v = 0.f; cur = nxt;
                if (r < 15) cf = __shfl(fl, r + 1);
            }
        }
    }

    asm volatile("s_waitcnt lgkmcnt(0)" ::: "memory");
    __builtin_amdgcn_sched_barrier(0);
    f16x8 a1[4];
#pragma unroll
    for (int kk = 0; kk < 4; ++kk)
        a1[kk] = *(const f16x8*)&s_h[w][mrow][kk * 32 + kgrp * 8];

#pragma unroll
    for (int n = 0; n < 16; ++n) {
        const int col = n * 16 + mrow;
        f32x4 acc = {0.f, 0.f, 0.f, 0.f};
#pragma unroll
        for (int kk = 0; kk < 4; ++kk) {
            const f16x8 b = *(const f16x8*)&W1t[(size_t)col * F + kk * 32 + kgrp * 8];
            acc = __builtin_amdgcn_mfma_f32_16x16x32_f16(a1[kk], b, acc, 0, 0, 0);
        }
        const float bj = b1[col];
#pragma unroll
        for (int r = 0; r < 4; ++r)
            s_h[w][kgrp * 4 + r][col] = (_Float16)(acc[r] + bj);
    }

    asm volatile("s_waitcnt lgkmcnt(0)" ::: "memory");
    __builtin_amdgcn_sched_barrier(0);

#pragma unroll
    for (int half = 0; half < 2; ++half) {
        const int c0 = half * 128 + 2 * lane;
        float a0 = 0.f, a1v = 0.f;
        int cur = __shfl(sv, 0);
        int cf  = __shfl(fl, 0);
#pragma unroll
        for (int r = 0; r < 16; ++r) {
            const f16x2 pv = *(const f16x2*)&s_h[w][r][c0];
            a0  += fmaxf((float)pv[0], 0.f);
            a1v += fmaxf((float)pv[1], 0.f);
            const int nxt = (r < 15) ? __shfl(sv, r + 1) : -2;
            if (nxt != cur) {
                if (cur >= 0) {
                    float* d = &S2[(size_t)cur * H1 + c0];
                    if (cf) { *(float2*)d = make_float2(a0, a1v); }
                    else    { atomicAdd(d, a0); atomicAdd(d + 1, a1v); }
                }
                a0 = 0.f; a1v = 0.f; cur = nxt;
                if (r < 15) cf = __shfl(fl, r + 1);
            }
        }
    }

    f16x8 a2[8];
#pragma unroll
    for (int k0 = 0; k0 < 8; ++k0)
        a2[k0] = *(const f16x8*)&s_h[w][mrow][k0 * 32 + kgrp * 8];

#pragma unroll
    for (int n = 0; n < 8; ++n) {
        const int col = n * 16 + mrow;
        f32x4 acc = {0.f, 0.f, 0.f, 0.f};
#pragma unroll
        for (int k0 = 0; k0 < 8; ++k0) {
            const f16x8 b = *(const f16x8*)&W2t[(size_t)col * H1 + k0 * 32 + kgrp * 8];
            acc = __builtin_amdgcn_mfma_f32_16x16x32_f16(a2[k0], b, acc, 0, 0, 0);
        }
        const float bj = b2[col];
#pragma unroll
        for (int r = 0; r < 4; ++r)
            s_h[w][kgrp * 4 + r][col] = (_Float16)(acc[r] + bj);
    }

    asm volatile("s_waitcnt lgkmcnt(0)" ::: "memory");
    __builtin_amdgcn_sched_barrier(0);

    {
        const int c0 = 2 * lane;
        float a0 = 0.f, a1v = 0.f;
        int cur = __shfl(sv, 0);
        int cf  = __shfl(fl, 0);
#pragma unroll
        for (int r = 0; r < 16; ++r) {
            const f16x2 pv = *(const f16x2*)&s_h[w][r][c0];
            a0  += fmaxf((float)pv[0], 0.f);
            a1v += fmaxf((float)pv[1], 0.f);
            const int nxt = (r < 15) ? __shfl(sv, r + 1) : -2;
            if (nxt != cur) {
                if (cur >= 0) {
                    float* d = &S4[(size_t)cur * H2 + c0];
                    if (cf) { *(float2*)d = make_float2(a0, a1v); }
                    else    { atomicAdd(d, a0); atomicAdd(d + 1, a1v); }
                }
                a0 = 0.f; a1v = 0.f; cur = nxt;
                if (r < 15) cf = __shfl(fl, r + 1);
            }
        }
    }
}

// ---------------------------------------------------------------------------
// Node kernel v7 (MFMA): 4 waves x 16 nodes, ZERO barriers.
// A-tile stacks [xn ; Sx] (32 rows) so h and S1 share one W1t B-stream:
//   GEMM_A: [xn;Sx]@W1t  -> h, S1 -> x2, S1 rows (f16) back to LDS
//   GEMM_B: [x2;S1]@W2t  -> h2, S3 -> x4 rows (f16) back to LDS
//   GEMM_C: x4@Wct (48-padded) -> out (cols < 40)
// ---------------------------------------------------------------------------
__global__ __launch_bounds__(256, 2) void node_kernel7(
    const float* __restrict__ x,
    const _Float16* __restrict__ W1t, const float* __restrict__ b1,
    const _Float16* __restrict__ W2t, const float* __restrict__ b2,
    const _Float16* __restrict__ Wct, const float* __restrict__ bc,
    const float* __restrict__ Sx, const float* __restrict__ S2,
    const float* __restrict__ S4, const int* __restrict__ start,
    float* __restrict__ out, int N)
{
    __shared__ _Float16 s_a[4][32][264];   // 67.6 KB; rows 0-15 = xn/x2/x4, 16-31 = Sx/S1

    const int tid  = threadIdx.x;
    const int lane = tid & 63;
    const int w    = tid >> 6;
    const int n0   = blockIdx.x * 64 + w * 16;
    const int mrow = lane & 15;
    const int kgrp = lane >> 4;

    // ---- load x rows (l2norm) + Sx rows -> f16 A-tile ----
#pragma unroll
    for (int r = 0; r < 16; ++r) {
        const int n = n0 + r;
        float v0 = 0.f, v1 = 0.f, u0 = 0.f, u1 = 0.f;
        if (n < N) {
            v0 = x[(size_t)n * F + lane];
            v1 = x[(size_t)n * F + 64 + lane];
            u0 = Sx[(size_t)n * F + lane];
            u1 = Sx[(size_t)n * F + 64 + lane];
        }
        const float ss = wave_sum64(v0 * v0 + v1 * v1);
        const float sc = 1.0f / fmaxf(sqrtf(ss), 1e-12f);
        s_a[w][r][lane]           = (_Float16)(v0 * sc);
        s_a[w][r][64 + lane]      = (_Float16)(v1 * sc);
        s_a[w][16 + r][lane]      = (_Float16)u0;
        s_a[w][16 + r][64 + lane] = (_Float16)u1;
    }

    // per-reg node row counts (C-layout row = kgrp*4 + q)
    float cntq[4];
#pragma unroll
    for (int q = 0; q < 4; ++q) {
        const int n = n0 + kgrp * 4 + q;
        cntq[q] = (n < N) ? (float)(start[n + 1] - start[n]) : 0.f;
    }

    asm volatile("s_waitcnt lgkmcnt(0)" ::: "memory");
    __builtin_amdgcn_sched_barrier(0);

    // ---- GEMM_A: [xn;Sx] @ W1t (M=32, N=256, K=128) ----
    f16x8 aA[2][4];
#pragma unroll
    for (int m = 0; m < 2; ++m)
#pragma unroll
        for (int kk = 0; kk < 4; ++kk)
            aA[m][kk] = *(const f16x8*)&s_a[w][m * 16 + mrow][kk * 32 + kgrp * 8];

#pragma unroll
    for (int n = 0; n < 16; ++n) {
        const int col = n * 16 + mrow;
        f32x4 accH = {0.f, 0.f, 0.f, 0.f};
        f32x4 accS = {0.f, 0.f, 0.f, 0.f};
#pragma unroll
        for (int kk = 0; kk < 4; ++kk) {
            const f16x8 b = *(const f16x8*)&W1t[(size_t)col * F + kk * 32 + kgrp * 8];
            accH = __builtin_amdgcn_mfma_f32_16x16x32_f16(aA[0][kk], b, accH, 0, 0, 0);
            accS = __builtin_amdgcn_mfma_f32_16x16x32_f16(aA[1][kk], b, accS, 0, 0, 0);
        }
        const float bj = b1[col];
#pragma unroll
        for (int q = 0; q < 4; ++q) {
            const int row = kgrp * 4 + q;
            const int n_  = n0 + row;
            const float h  = accH[q] + bj;
            const float S1 = accS[q] + cntq[q] * bj;
            const float x1 = fmaxf(h + 0.9f * S1, 0.f);
            const float s2v = (n_ < N) ? S2[(size_t)n_ * H1 + col] : 0.f;
            const float x2 = 0.9f * (x1 + s2v) + 0.1f * h;
            s_a[w][row][col]      = (_Float16)x2;
            s_a[w][16 + row][col] = (_Float16)S1;
        }
    }

    asm volatile("s_waitcnt lgkmcnt(0)" ::: "memory");
    __builtin_amdgcn_sched_barrier(0);

    // ---- GEMM_B: [x2;S1] @ W2t (M=32, N=128, K=256) ----
    f16x8 aB[2][8];
#pragma unroll
    for (int m = 0; m < 2; ++m)
#pragma unroll
        for (int k0 = 0; k0 < 8; ++k0)
            aB[m][k0] = *(const f16x8*)&s_a[w][m * 16 + mrow][k0 * 32 + kgrp * 8];

#pragma unroll
    for (int n = 0; n < 8; ++n) {
        const int col = n * 16 + mrow;
        f32x4 accH = {0.f, 0.f, 0.f, 0.f};
        f32x4 accS = {0.f, 0.f, 0.f, 0.f};
#pragma unroll
        for (int k0 = 0; k0 < 8; ++k0) {
            const f16x8 b = *(const f16x8*)&W2t[(size_t)col * H1 + k0 * 32 + kgrp * 8];
            accH = __builtin_amdgcn_mfma_f32_16x16x32_f16(aB[0][k0], b, accH, 0, 0, 0);
            accS = __builtin_amdgcn_mfma_f32_16x16x32_f16(aB[1][k0], b, accS, 0, 0, 0);
        }
        const float bj = b2[col];
#pragma unroll
        for (int q = 0; q < 4; ++q) {
            const int row = kgrp * 4 + q;
            const int n_  = n0 + row;
            const float h2 = accH[q] + bj;
            const float S3 = accS[q] + cntq[q] * bj;
            const float x3 = fmaxf(h2 + 0.9f * S3, 0.f);
            const float s4v = (n_ < N) ? S4[(size_t)n_ * H2 + col] : 0.f;
            s_a[w][row][col] = (_Float16)(0.9f * (x3 + s4v) + 0.1f * h2);
        }
    }

    asm volatile("s_waitcnt lgkmcnt(0)" ::: "memory");
    __builtin_amdgcn_sched_barrier(0);

    // ---- GEMM_C: x4 @ Wct (M=16, N=48 padded, K=128) ----
    f16x8 aC[4];
#pragma unroll
    for (int kk = 0; kk < 4; ++kk)
        aC[kk] = *(const f16x8*)&s_a[w][mrow][kk * 32 + kgrp * 8];

#pragma unroll
    for (int n = 0; n < 3; ++n) {
        const int col = n * 16 + mrow;
        f32x4 acc = {0.f, 0.f, 0.f, 0.f};
#pragma unroll
        for (int kk = 0; kk < 4; ++kk) {
            const f16x8 b = *(const f16x8*)&Wct[(size_t)col * F + kk * 32 + kgrp * 8];
            acc = __builtin_amdgcn_mfma_f32_16x16x32_f16(aC[kk], b, acc, 0, 0, 0);
        }
        if (col < C) {
            const float bcc = bc[col];
#pragma unroll
            for (int q = 0; q < 4; ++q) {
                const int n_ = n0 + kgrp * 4 + q;
                if (n_ < N) out[(size_t)n_ * C + col] = acc[q] + bcc;
            }
        }
    }
}

extern "C" void kernel_launch(void* const* d_in, const int* in_sizes, int n_in,
                              void* d_out, int out_size, void* d_ws, size_t ws_size,
                              hipStream_t stream) {
    const float* x   = (const float*)d_in[0];
    const float* nbx = (const float*)d_in[1];
    const float* W1  = (const float*)d_in[2];
    const float* b1  = (const float*)d_in[3];
    const float* W2  = (const float*)d_in[4];
    const float* b2  = (const float*)d_in[5];
    const float* Wc  = (const float*)d_in[6];
    const float* bc  = (const float*)d_in[7];
    const int*   seg = (const int*)d_in[8];

    const int N = in_sizes[0] / F;   // 50000
    const int E = in_sizes[8];       // 600000
    float* out = (float*)d_out;

    // workspace layout:
    // [Sx f32 N*F | S2 f32 N*H1 | S4 f32 N*H2 | hist N | cursor N | bsum 256] <- zeroed
    // [start N+1 | ord E | W1t f16 | W2t f16 | Wct f16]
    float* Sx    = (float*)d_ws;
    float* S2    = Sx + (size_t)N * F;
    float* S4    = S2 + (size_t)N * H1;
    int*   hist  = (int*)(S4 + (size_t)N * H2);
    int*   cursor= hist + N;
    int*   bsum  = cursor + N;
    int*   start = bsum + 256;
    int*   ord   = start + (N + 1);
    char*  wrest = (char*)(ord + E);
    _Float16* W1t = (_Float16*)(((uintptr_t)wrest + 15) & ~(uintptr_t)15);
    _Float16* W2t = W1t + (size_t)H1 * F;
    _Float16* Wct = W2t + (size_t)H2 * H1;

    const size_t zero_bytes = ((size_t)N * (F + H1 + H2)) * 4 + (size_t)N * 8 + 1024;
    hipMemsetAsync(d_ws, 0, zero_bytes, stream);

    prep_weights<<<128, 256, 0, stream>>>(W1, W2, Wc, W1t, W2t, Wct);

    const int B = (N + 255) / 256;
    k_hist   <<<(E + 255) / 256, 256, 0, stream>>>(seg, hist, E);
    k_scan1  <<<B, 256, 0, stream>>>(hist, bsum, N);
    k_scan2  <<<1, 256, 0, stream>>>(bsum, B);
    k_scan3  <<<B, 256, 0, stream>>>(hist, bsum, start, cursor, N, E);
    k_scatter<<<(E + 255) / 256, 256, 0, stream>>>(seg, start, cursor, ord, E);

    edge_kernel6<<<(E + 63) / 64, 256, 0, stream>>>(
        nbx, seg, ord, start, W1t, b1, W2t, b2, Sx, S2, S4, E);
    node_kernel7<<<(N + 63) / 64, 256, 0, stream>>>(
        x, W1t, b1, W2t, b2, Wct, bc, Sx, S2, S4, start, out, N);
}

// Round 8
// 565.706 us; speedup vs baseline: 4.4294x; 1.5322x over previous
//
#include <hip/hip_runtime.h>

constexpr int F  = 128;   // input feature dim
constexpr int H1 = 256;
constexpr int H2 = 128;
constexpr int C  = 40;

using f32x4 = __attribute__((ext_vector_type(4))) float;
using f16x8 = __attribute__((ext_vector_type(8))) _Float16;
using f16x2 = __attribute__((ext_vector_type(2))) _Float16;

__device__ __forceinline__ float wave_sum64(float v) {
#pragma unroll
    for (int off = 32; off > 0; off >>= 1) v += __shfl_xor(v, off, 64);
    return v;
}

// ---------------------------------------------------------------------------
// Weight prep: transpose + fp16-convert W1, W2, Wc into workspace.
// ---------------------------------------------------------------------------
__global__ __launch_bounds__(256) void prep_weights(
    const float* __restrict__ W1, const float* __restrict__ W2,
    const float* __restrict__ Wc,
    _Float16* __restrict__ W1t, _Float16* __restrict__ W2t,
    _Float16* __restrict__ Wct)
{
    const int i = blockIdx.x * 256 + threadIdx.x;
    if (i < H1 * F) {
        const int j = i >> 7, f = i & 127;
        W1t[i] = (_Float16)W1[(size_t)f * H1 + j];
    }
    if (i < H2 * H1) {
        const int j = i >> 8, k = i & 255;
        W2t[i] = (_Float16)W2[(size_t)k * H2 + j];
    }
    if (i < 48 * F) {
        const int c = i >> 7, k = i & 127;
        Wct[i] = (c < C) ? (_Float16)Wc[(size_t)k * C + c] : (_Float16)0.f;
    }
}

// ---------------------------------------------------------------------------
// Counting sort of edges by segment: hist -> 3-pass scan -> scatter.
// ---------------------------------------------------------------------------
__global__ __launch_bounds__(256) void k_hist(
    const int* __restrict__ seg, int* __restrict__ hist, int E)
{
    const int e = blockIdx.x * 256 + threadIdx.x;
    if (e < E) atomicAdd(&hist[seg[e]], 1);
}

__global__ __launch_bounds__(256) void k_scan1(
    const int* __restrict__ hist, int* __restrict__ bsum, int N)
{
    __shared__ int s[256];
    const int t = threadIdx.x;
    const int i = blockIdx.x * 256 + t;
    s[t] = (i < N) ? hist[i] : 0;
    __syncthreads();
#pragma unroll
    for (int off = 128; off > 0; off >>= 1) {
        if (t < off) s[t] += s[t + off];
        __syncthreads();
    }
    if (t == 0) bsum[blockIdx.x] = s[0];
}

__global__ __launch_bounds__(256) void k_scan2(int* __restrict__ bsum, int B)
{
    __shared__ int s[256];
    const int t = threadIdx.x;
    const int v = (t < B) ? bsum[t] : 0;
    s[t] = v;
    __syncthreads();
#pragma unroll
    for (int off = 1; off < 256; off <<= 1) {
        const int u = (t >= off) ? s[t - off] : 0;
        __syncthreads();
        s[t] += u;
        __syncthreads();
    }
    if (t < B) bsum[t] = s[t] - v;   // exclusive block offsets
}

__global__ __launch_bounds__(256) void k_scan3(
    const int* __restrict__ hist, const int* __restrict__ bsum,
    int* __restrict__ start, int* __restrict__ cursor, int N, int E)
{
    __shared__ int s[256];
    const int t = threadIdx.x;
    const int i = blockIdx.x * 256 + t;
    const int v = (i < N) ? hist[i] : 0;
    s[t] = v;
    __syncthreads();
#pragma unroll
    for (int off = 1; off < 256; off <<= 1) {
        const int u = (t >= off) ? s[t - off] : 0;
        __syncthreads();
        s[t] += u;
        __syncthreads();
    }
    if (i < N) {
        start[i]  = bsum[blockIdx.x] + s[t] - v;
        cursor[i] = 0;
    }
    if (i == 0) start[N] = E;
}

__global__ __launch_bounds__(256) void k_scatter(
    const int* __restrict__ seg, const int* __restrict__ start,
    int* __restrict__ cursor, int* __restrict__ ord, int E)
{
    const int e = blockIdx.x * 256 + threadIdx.x;
    if (e < E) {
        const int s = seg[e];
        const int r = atomicAdd(&cursor[s], 1);
        ord[start[s] + r] = e;
    }
}

// ---------------------------------------------------------------------------
// Edge kernel v8: COLUMN-SPLIT GEMMs over a block-shared 64-row A-tile.
//   Phase A (per-wave, own 16 rows): gather, l2norm, register Sx agg,
//     f16 rows -> s_h.                                          [barrier]
//   GEMM1: all waves load A-frags (64 rows) to regs             [barrier]
//     wave w computes cols [w*64,(w+1)*64): 4 col-tiles; each = 4 B-loads
//     feeding 16 MFMAs (B double-buffered); n_h -> s_h in place [barrier]
//   S2 agg (per-wave window rows, f16x2 pairs, relu on read)
//   GEMM2: wave w computes cols [w*32,(w+1)*32): per col-tile 8 B-loads,
//     A re-read from LDS per row-tile, 32 MFMAs; acc held       [barrier]
//   n_h2 -> s_h                                                 [barrier]
//   S4 agg (per-wave window rows)
// ---------------------------------------------------------------------------
__global__ __launch_bounds__(256, 3) void edge_kernel8(
    const float* __restrict__ nbx, const int* __restrict__ seg,
    const int* __restrict__ ord, const int* __restrict__ start,
    const _Float16* __restrict__ W1t, const float* __restrict__ b1,
    const _Float16* __restrict__ W2t, const float* __restrict__ b2,
    float* __restrict__ Sx, float* __restrict__ S2, float* __restrict__ S4,
    int E)
{
    __shared__ _Float16 s_h[64][264];   // 33.8 KB block-shared

    const int tid   = threadIdx.x;
    const int lane  = tid & 63;
    const int w     = tid >> 6;
    const int wrow0 = w * 16;                    // window rows in s_h
    const int wbase = blockIdx.x * 64 + wrow0;   // sorted-index window start
    const int mrow  = lane & 15;
    const int kgrp  = lane >> 4;

    const int  p    = wbase + mrow;
    const bool pin  = (p < E);
    const int  edge = pin ? ord[p] : 0;

    // ---- Phase A: gather 16 rows ----
    float va[16][2];
#pragma unroll
    for (int r = 0; r < 16; ++r) {
        const int er = __shfl(edge, r);
        const bool v = (wbase + r < E);
        va[r][0] = v ? nbx[(size_t)er * F + lane] : 0.f;
        va[r][1] = v ? nbx[(size_t)er * F + 64 + lane] : 0.f;
    }

    const int sv = pin ? seg[edge] : -1;
    int fl = 0;
    if (pin) {
        const int s0 = start[sv], s1 = start[sv + 1];
        fl = (s0 >= wbase) && (s1 <= wbase + 16);
    }

#pragma unroll
    for (int r = 0; r < 16; ++r) {
        const float ss = wave_sum64(va[r][0] * va[r][0] + va[r][1] * va[r][1]);
        const float sc = 1.0f / fmaxf(sqrtf(ss), 1e-12f);
        va[r][0] *= sc; va[r][1] *= sc;
        s_h[wrow0 + r][lane]      = (_Float16)va[r][0];
        s_h[wrow0 + r][64 + lane] = (_Float16)va[r][1];
    }

    // ---- Sx aggregation from registers ----
    {
        float a0 = 0.f, a1v = 0.f;
        int cur = __shfl(sv, 0);
        int cf  = __shfl(fl, 0);
#pragma unroll
        for (int r = 0; r < 16; ++r) {
            a0 += va[r][0]; a1v += va[r][1];
            const int nxt = (r < 15) ? __shfl(sv, r + 1) : -2;
            if (nxt != cur) {
                if (cur >= 0) {
                    float* d = &Sx[(size_t)cur * F + lane];
                    if (cf) { d[0] = a0; d[64] = a1v; }
                    else    { atomicAdd(d, a0); atomicAdd(d + 64, a1v); }
                }
                a0 = 0.f; a1v = 0.f; cur = nxt;
                if (r < 15) cf = __shfl(fl, r + 1);
            }
        }
    }

    __syncthreads();   // full 64-row A-tile visible

    // ---- GEMM1: load ALL A-frags (64 rows) into registers ----
    f16x8 aA[4][4];
#pragma unroll
    for (int m = 0; m < 4; ++m)
#pragma unroll
        for (int kk = 0; kk < 4; ++kk)
            aA[m][kk] = *(const f16x8*)&s_h[m * 16 + mrow][kk * 32 + kgrp * 8];

    asm volatile("s_waitcnt lgkmcnt(0)" ::: "memory");
    __builtin_amdgcn_sched_barrier(0);
    __syncthreads();   // everyone holds A-frags; s_h may be overwritten

    {
        const int colbase = w * 64 + mrow;
        float bj1[4];
#pragma unroll
        for (int ct = 0; ct < 4; ++ct) bj1[ct] = b1[colbase + ct * 16];

        f16x8 b[4], bn[4];
#pragma unroll
        for (int kk = 0; kk < 4; ++kk)
            b[kk] = *(const f16x8*)&W1t[(size_t)colbase * F + kk * 32 + kgrp * 8];

#pragma unroll
        for (int ct = 0; ct < 4; ++ct) {
            const int col = colbase + ct * 16;
            if (ct < 3) {
#pragma unroll
                for (int kk = 0; kk < 4; ++kk)
                    bn[kk] = *(const f16x8*)&W1t[(size_t)(col + 16) * F + kk * 32 + kgrp * 8];
            }
            f32x4 acc[4];
#pragma unroll
            for (int m = 0; m < 4; ++m) acc[m] = (f32x4){0.f, 0.f, 0.f, 0.f};
#pragma unroll
            for (int kk = 0; kk < 4; ++kk)
#pragma unroll
                for (int m = 0; m < 4; ++m)
                    acc[m] = __builtin_amdgcn_mfma_f32_16x16x32_f16(aA[m][kk], b[kk], acc[m], 0, 0, 0);
#pragma unroll
            for (int m = 0; m < 4; ++m)
#pragma unroll
                for (int q = 0; q < 4; ++q)
                    s_h[m * 16 + kgrp * 4 + q][col] = (_Float16)(acc[m][q] + bj1[ct]);
#pragma unroll
            for (int kk = 0; kk < 4; ++kk) b[kk] = bn[kk];
        }
    }
    __syncthreads();   // n_h complete

    // ---- S2 aggregation (own window rows; relu on read) ----
#pragma unroll
    for (int half = 0; half < 2; ++half) {
        const int c0 = half * 128 + 2 * lane;
        float a0 = 0.f, a1v = 0.f;
        int cur = __shfl(sv, 0);
        int cf  = __shfl(fl, 0);
#pragma unroll
        for (int r = 0; r < 16; ++r) {
            const f16x2 pv = *(const f16x2*)&s_h[wrow0 + r][c0];
            a0  += fmaxf((float)pv[0], 0.f);
            a1v += fmaxf((float)pv[1], 0.f);
            const int nxt = (r < 15) ? __shfl(sv, r + 1) : -2;
            if (nxt != cur) {
                if (cur >= 0) {
                    float* d = &S2[(size_t)cur * H1 + c0];
                    if (cf) { *(float2*)d = make_float2(a0, a1v); }
                    else    { atomicAdd(d, a0); atomicAdd(d + 1, a1v); }
                }
                a0 = 0.f; a1v = 0.f; cur = nxt;
                if (r < 15) cf = __shfl(fl, r + 1);
            }
        }
    }

    // ---- GEMM2: wave w owns cols [w*32,(w+1)*32); A re-read from LDS ----
    f32x4 acc2[2][4];
#pragma unroll
    for (int ct = 0; ct < 2; ++ct)
#pragma unroll
        for (int m = 0; m < 4; ++m) acc2[ct][m] = (f32x4){0.f, 0.f, 0.f, 0.f};

    float bj2[2];
#pragma unroll
    for (int ct = 0; ct < 2; ++ct) bj2[ct] = b2[w * 32 + ct * 16 + mrow];

#pragma unroll
    for (int ct = 0; ct < 2; ++ct) {
        const int col = w * 32 + ct * 16 + mrow;
        f16x8 b[8];
#pragma unroll
        for (int k0 = 0; k0 < 8; ++k0)
            b[k0] = *(const f16x8*)&W2t[(size_t)col * H1 + k0 * 32 + kgrp * 8];
#pragma unroll
        for (int m = 0; m < 4; ++m) {
            f16x8 a[8];
#pragma unroll
            for (int k0 = 0; k0 < 8; ++k0)
                a[k0] = *(const f16x8*)&s_h[m * 16 + mrow][k0 * 32 + kgrp * 8];
#pragma unroll
            for (int k0 = 0; k0 < 8; ++k0)
                acc2[ct][m] = __builtin_amdgcn_mfma_f32_16x16x32_f16(a[k0], b[k0], acc2[ct][m], 0, 0, 0);
        }
    }
    __syncthreads();   // all GEMM2 LDS reads complete

    // ---- write n_h2 ----
#pragma unroll
    for (int ct = 0; ct < 2; ++ct) {
        const int col = w * 32 + ct * 16 + mrow;
#pragma unroll
        for (int m = 0; m < 4; ++m)
#pragma unroll
            for (int q = 0; q < 4; ++q)
                s_h[m * 16 + kgrp * 4 + q][col] = (_Float16)(acc2[ct][m][q] + bj2[ct]);
    }
    __syncthreads();   // n_h2 complete

    // ---- S4 aggregation (own window rows; relu on read) ----
    {
        const int c0 = 2 * lane;
        float a0 = 0.f, a1v = 0.f;
        int cur = __shfl(sv, 0);
        int cf  = __shfl(fl, 0);
#pragma unroll
        for (int r = 0; r < 16; ++r) {
            const f16x2 pv = *(const f16x2*)&s_h[wrow0 + r][c0];
            a0  += fmaxf((float)pv[0], 0.f);
            a1v += fmaxf((float)pv[1], 0.f);
            const int nxt = (r < 15) ? __shfl(sv, r + 1) : -2;
            if (nxt != cur) {
                if (cur >= 0) {
                    float* d = &S4[(size_t)cur * H2 + c0];
                    if (cf) { *(float2*)d = make_float2(a0, a1v); }
                    else    { atomicAdd(d, a0); atomicAdd(d + 1, a1v); }
                }
                a0 = 0.f; a1v = 0.f; cur = nxt;
                if (r < 15) cf = __shfl(fl, r + 1);
            }
        }
    }
}

// ---------------------------------------------------------------------------
// Node kernel v7 (unchanged): 4 waves x 16 nodes, zero barriers, MFMA.
// ---------------------------------------------------------------------------
__global__ __launch_bounds__(256, 2) void node_kernel7(
    const float* __restrict__ x,
    const _Float16* __restrict__ W1t, const float* __restrict__ b1,
    const _Float16* __restrict__ W2t, const float* __restrict__ b2,
    const _Float16* __restrict__ Wct, const float* __restrict__ bc,
    const float* __restrict__ Sx, const float* __restrict__ S2,
    const float* __restrict__ S4, const int* __restrict__ start,
    float* __restrict__ out, int N)
{
    __shared__ _Float16 s_a[4][32][264];

    const int tid  = threadIdx.x;
    const int lane = tid & 63;
    const int w    = tid >> 6;
    const int n0   = blockIdx.x * 64 + w * 16;
    const int mrow = lane & 15;
    const int kgrp = lane >> 4;

#pragma unroll
    for (int r = 0; r < 16; ++r) {
        const int n = n0 + r;
        float v0 = 0.f, v1 = 0.f, u0 = 0.f, u1 = 0.f;
        if (n < N) {
            v0 = x[(size_t)n * F + lane];
            v1 = x[(size_t)n * F + 64 + lane];
            u0 = Sx[(size_t)n * F + lane];
            u1 = Sx[(size_t)n * F + 64 + lane];
        }
        const float ss = wave_sum64(v0 * v0 + v1 * v1);
        const float sc = 1.0f / fmaxf(sqrtf(ss), 1e-12f);
        s_a[w][r][lane]           = (_Float16)(v0 * sc);
        s_a[w][r][64 + lane]      = (_Float16)(v1 * sc);
        s_a[w][16 + r][lane]      = (_Float16)u0;
        s_a[w][16 + r][64 + lane] = (_Float16)u1;
    }

    float cntq[4];
#pragma unroll
    for (int q = 0; q < 4; ++q) {
        const int n = n0 + kgrp * 4 + q;
        cntq[q] = (n < N) ? (float)(start[n + 1] - start[n]) : 0.f;
    }

    asm volatile("s_waitcnt lgkmcnt(0)" ::: "memory");
    __builtin_amdgcn_sched_barrier(0);

    f16x8 aA[2][4];
#pragma unroll
    for (int m = 0; m < 2; ++m)
#pragma unroll
        for (int kk = 0; kk < 4; ++kk)
            aA[m][kk] = *(const f16x8*)&s_a[w][m * 16 + mrow][kk * 32 + kgrp * 8];

#pragma unroll
    for (int n = 0; n < 16; ++n) {
        const int col = n * 16 + mrow;
        f32x4 accH = {0.f, 0.f, 0.f, 0.f};
        f32x4 accS = {0.f, 0.f, 0.f, 0.f};
#pragma unroll
        for (int kk = 0; kk < 4; ++kk) {
            const f16x8 b = *(const f16x8*)&W1t[(size_t)col * F + kk * 32 + kgrp * 8];
            accH = __builtin_amdgcn_mfma_f32_16x16x32_f16(aA[0][kk], b, accH, 0, 0, 0);
            accS = __builtin_amdgcn_mfma_f32_16x16x32_f16(aA[1][kk], b, accS, 0, 0, 0);
        }
        const float bj = b1[col];
#pragma unroll
        for (int q = 0; q < 4; ++q) {
            const int row = kgrp * 4 + q;
            const int n_  = n0 + row;
            const float h  = accH[q] + bj;
            const float S1 = accS[q] + cntq[q] * bj;
            const float x1 = fmaxf(h + 0.9f * S1, 0.f);
            const float s2v = (n_ < N) ? S2[(size_t)n_ * H1 + col] : 0.f;
            const float x2 = 0.9f * (x1 + s2v) + 0.1f * h;
            s_a[w][row][col]      = (_Float16)x2;
            s_a[w][16 + row][col] = (_Float16)S1;
        }
    }

    asm volatile("s_waitcnt lgkmcnt(0)" ::: "memory");
    __builtin_amdgcn_sched_barrier(0);

    f16x8 aB[2][8];
#pragma unroll
    for (int m = 0; m < 2; ++m)
#pragma unroll
        for (int k0 = 0; k0 < 8; ++k0)
            aB[m][k0] = *(const f16x8*)&s_a[w][m * 16 + mrow][k0 * 32 + kgrp * 8];

#pragma unroll
    for (int n = 0; n < 8; ++n) {
        const int col = n * 16 + mrow;
        f32x4 accH = {0.f, 0.f, 0.f, 0.f};
        f32x4 accS = {0.f, 0.f, 0.f, 0.f};
#pragma unroll
        for (int k0 = 0; k0 < 8; ++k0) {
            const f16x8 b = *(const f16x8*)&W2t[(size_t)col * H1 + k0 * 32 + kgrp * 8];
            accH = __builtin_amdgcn_mfma_f32_16x16x32_f16(aB[0][k0], b, accH, 0, 0, 0);
            accS = __builtin_amdgcn_mfma_f32_16x16x32_f16(aB[1][k0], b, accS, 0, 0, 0);
        }
        const float bj = b2[col];
#pragma unroll
        for (int q = 0; q < 4; ++q) {
            const int row = kgrp * 4 + q;
            const int n_  = n0 + row;
            const float h2 = accH[q] + bj;
            const float S3 = accS[q] + cntq[q] * bj;
            const float x3 = fmaxf(h2 + 0.9f * S3, 0.f);
            const float s4v = (n_ < N) ? S4[(size_t)n_ * H2 + col] : 0.f;
            s_a[w][row][col] = (_Float16)(0.9f * (x3 + s4v) + 0.1f * h2);
        }
    }

    asm volatile("s_waitcnt lgkmcnt(0)" ::: "memory");
    __builtin_amdgcn_sched_barrier(0);

    f16x8 aC[4];
#pragma unroll
    for (int kk = 0; kk < 4; ++kk)
        aC[kk] = *(const f16x8*)&s_a[w][mrow][kk * 32 + kgrp * 8];

#pragma unroll
    for (int n = 0; n < 3; ++n) {
        const int col = n * 16 + mrow;
        f32x4 acc = {0.f, 0.f, 0.f, 0.f};
#pragma unroll
        for (int kk = 0; kk < 4; ++kk) {
            const f16x8 b = *(const f16x8*)&Wct[(size_t)col * F + kk * 32 + kgrp * 8];
            acc = __builtin_amdgcn_mfma_f32_16x16x32_f16(aC[kk], b, acc, 0, 0, 0);
        }
        if (col < C) {
            const float bcc = bc[col];
#pragma unroll
            for (int q = 0; q < 4; ++q) {
                const int n_ = n0 + kgrp * 4 + q;
                if (n_ < N) out[(size_t)n_ * C + col] = acc[q] + bcc;
            }
        }
    }
}

extern "C" void kernel_launch(void* const* d_in, const int* in_sizes, int n_in,
                              void* d_out, int out_size, void* d_ws, size_t ws_size,
                              hipStream_t stream) {
    const float* x   = (const float*)d_in[0];
    const float* nbx = (const float*)d_in[1];
    const float* W1  = (const float*)d_in[2];
    const float* b1  = (const float*)d_in[3];
    const float* W2  = (const float*)d_in[4];
    const float* b2  = (const float*)d_in[5];
    const float* Wc  = (const float*)d_in[6];
    const float* bc  = (const float*)d_in[7];
    const int*   seg = (const int*)d_in[8];

    const int N = in_sizes[0] / F;   // 50000
    const int E = in_sizes[8];       // 600000
    float* out = (float*)d_out;

    float* Sx    = (float*)d_ws;
    float* S2    = Sx + (size_t)N * F;
    float* S4    = S2 + (size_t)N * H1;
    int*   hist  = (int*)(S4 + (size_t)N * H2);
    int*   cursor= hist + N;
    int*   bsum  = cursor + N;
    int*   start = bsum + 256;
    int*   ord   = start + (N + 1);
    char*  wrest = (char*)(ord + E);
    _Float16* W1t = (_Float16*)(((uintptr_t)wrest + 15) & ~(uintptr_t)15);
    _Float16* W2t = W1t + (size_t)H1 * F;
    _Float16* Wct = W2t + (size_t)H2 * H1;

    const size_t zero_bytes = ((size_t)N * (F + H1 + H2)) * 4 + (size_t)N * 8 + 1024;
    hipMemsetAsync(d_ws, 0, zero_bytes, stream);

    prep_weights<<<128, 256, 0, stream>>>(W1, W2, Wc, W1t, W2t, Wct);

    const int B = (N + 255) / 256;
    k_hist   <<<(E + 255) / 256, 256, 0, stream>>>(seg, hist, E);
    k_scan1  <<<B, 256, 0, stream>>>(hist, bsum, N);
    k_scan2  <<<1, 256, 0, stream>>>(bsum, B);
    k_scan3  <<<B, 256, 0, stream>>>(hist, bsum, start, cursor, N, E);
    k_scatter<<<(E + 255) / 256, 256, 0, stream>>>(seg, start, cursor, ord, E);

    edge_kernel8<<<(E + 63) / 64, 256, 0, stream>>>(
        nbx, seg, ord, start, W1t, b1, W2t, b2, Sx, S2, S4, E);
    node_kernel7<<<(N + 63) / 64, 256, 0, stream>>>(
        x, W1t, b1, W2t, b2, Wct, bc, Sx, S2, S4, start, out, N);
}

// Round 9
// 519.870 us; speedup vs baseline: 4.8199x; 1.0882x over previous
//
#include <hip/hip_runtime.h>

constexpr int F  = 128;   // input feature dim
constexpr int H1 = 256;
constexpr int H2 = 128;
constexpr int C  = 40;

using f32x4 = __attribute__((ext_vector_type(4))) float;
using f16x8 = __attribute__((ext_vector_type(8))) _Float16;
using f16x2 = __attribute__((ext_vector_type(2))) _Float16;

__device__ __forceinline__ float wave_sum64(float v) {
#pragma unroll
    for (int off = 32; off > 0; off >>= 1) v += __shfl_xor(v, off, 64);
    return v;
}

// ---------------------------------------------------------------------------
// Weight prep: transpose + fp16-convert W1, W2, Wc into workspace.
// ---------------------------------------------------------------------------
__global__ __launch_bounds__(256) void prep_weights(
    const float* __restrict__ W1, const float* __restrict__ W2,
    const float* __restrict__ Wc,
    _Float16* __restrict__ W1t, _Float16* __restrict__ W2t,
    _Float16* __restrict__ Wct)
{
    const int i = blockIdx.x * 256 + threadIdx.x;
    if (i < H1 * F) {
        const int j = i >> 7, f = i & 127;
        W1t[i] = (_Float16)W1[(size_t)f * H1 + j];
    }
    if (i < H2 * H1) {
        const int j = i >> 8, k = i & 255;
        W2t[i] = (_Float16)W2[(size_t)k * H2 + j];
    }
    if (i < 48 * F) {
        const int c = i >> 7, k = i & 127;
        Wct[i] = (c < C) ? (_Float16)Wc[(size_t)k * C + c] : (_Float16)0.f;
    }
}

// ---------------------------------------------------------------------------
// Counting sort of edges by segment: hist -> 3-pass scan -> scatter.
// ---------------------------------------------------------------------------
__global__ __launch_bounds__(256) void k_hist(
    const int* __restrict__ seg, int* __restrict__ hist, int E)
{
    const int e = blockIdx.x * 256 + threadIdx.x;
    if (e < E) atomicAdd(&hist[seg[e]], 1);
}

__global__ __launch_bounds__(256) void k_scan1(
    const int* __restrict__ hist, int* __restrict__ bsum, int N)
{
    __shared__ int s[256];
    const int t = threadIdx.x;
    const int i = blockIdx.x * 256 + t;
    s[t] = (i < N) ? hist[i] : 0;
    __syncthreads();
#pragma unroll
    for (int off = 128; off > 0; off >>= 1) {
        if (t < off) s[t] += s[t + off];
        __syncthreads();
    }
    if (t == 0) bsum[blockIdx.x] = s[0];
}

__global__ __launch_bounds__(256) void k_scan2(int* __restrict__ bsum, int B)
{
    __shared__ int s[256];
    const int t = threadIdx.x;
    const int v = (t < B) ? bsum[t] : 0;
    s[t] = v;
    __syncthreads();
#pragma unroll
    for (int off = 1; off < 256; off <<= 1) {
        const int u = (t >= off) ? s[t - off] : 0;
        __syncthreads();
        s[t] += u;
        __syncthreads();
    }
    if (t < B) bsum[t] = s[t] - v;   // exclusive block offsets
}

__global__ __launch_bounds__(256) void k_scan3(
    const int* __restrict__ hist, const int* __restrict__ bsum,
    int* __restrict__ start, int* __restrict__ cursor, int N, int E)
{
    __shared__ int s[256];
    const int t = threadIdx.x;
    const int i = blockIdx.x * 256 + t;
    const int v = (i < N) ? hist[i] : 0;
    s[t] = v;
    __syncthreads();
#pragma unroll
    for (int off = 1; off < 256; off <<= 1) {
        const int u = (t >= off) ? s[t - off] : 0;
        __syncthreads();
        s[t] += u;
        __syncthreads();
    }
    if (i < N) {
        start[i]  = bsum[blockIdx.x] + s[t] - v;
        cursor[i] = 0;
    }
    if (i == 0) start[N] = E;
}

__global__ __launch_bounds__(256) void k_scatter(
    const int* __restrict__ seg, const int* __restrict__ start,
    int* __restrict__ cursor, int* __restrict__ ord, int E)
{
    const int e = blockIdx.x * 256 + threadIdx.x;
    if (e < E) {
        const int s = seg[e];
        const int r = atomicAdd(&cursor[s], 1);
        ord[start[s] + r] = e;
    }
}

// ---------------------------------------------------------------------------
// Edge kernel v9: 2 tiles x 64 edges per block, pipelined gather.
//   Prologue: meta + gather loads for BOTH tiles (tile1's 32 loads stay in
//   flight across tile0's entire compute).
//   Per tile: l2norm -> s_nb | Sx agg (regs) | [bar] GEMM1 (A re-read from
//   s_nb, B dbuf, writes s_nh) | [bar] S2 agg + GEMM2 (A from s_nh, writes
//   n_h2 into s_nb - disjoint) | [bar] S4 agg | [bar].
//   LDS: s_nb 17.4 KB + s_nh 33.8 KB = 51.2 KB -> 3 blocks/CU.
// ---------------------------------------------------------------------------
__global__ __launch_bounds__(256, 3) void edge_kernel9(
    const float* __restrict__ nbx, const int* __restrict__ seg,
    const int* __restrict__ ord, const int* __restrict__ start,
    const _Float16* __restrict__ W1t, const float* __restrict__ b1,
    const _Float16* __restrict__ W2t, const float* __restrict__ b2,
    float* __restrict__ Sx, float* __restrict__ S2, float* __restrict__ S4,
    int E)
{
    __shared__ _Float16 s_nb[64][136];   // nb, later n_h2
    __shared__ _Float16 s_nh[64][264];   // n_h

    const int tid   = threadIdx.x;
    const int lane  = tid & 63;
    const int w     = tid >> 6;
    const int wrow0 = w * 16;
    const int mrow  = lane & 15;
    const int kgrp  = lane >> 4;
    const int base  = blockIdx.x * 128;

    // ---- prologue: meta + gathers for both tiles ----
    int edg[2], sv[2], fl[2];
    float va[2][16][2];
#pragma unroll
    for (int t = 0; t < 2; ++t) {
        const int wbase = base + t * 64 + wrow0;
        const int p     = wbase + mrow;
        const bool pin  = (p < E);
        edg[t] = pin ? ord[p] : 0;
        sv[t]  = pin ? seg[edg[t]] : -1;
        fl[t]  = 0;
        if (pin) {
            const int s0 = start[sv[t]], s1 = start[sv[t] + 1];
            fl[t] = (s0 >= wbase) && (s1 <= wbase + 16);
        }
#pragma unroll
        for (int r = 0; r < 16; ++r) {
            const int er = __shfl(edg[t], r);
            const bool v = (wbase + r < E);
            va[t][r][0] = v ? nbx[(size_t)er * F + lane] : 0.f;
            va[t][r][1] = v ? nbx[(size_t)er * F + 64 + lane] : 0.f;
        }
    }

#pragma unroll
    for (int t = 0; t < 2; ++t) {
        // ---- l2norm + LDS store ----
#pragma unroll
        for (int r = 0; r < 16; ++r) {
            const float ss = wave_sum64(va[t][r][0] * va[t][r][0] +
                                        va[t][r][1] * va[t][r][1]);
            const float sc = 1.0f / fmaxf(sqrtf(ss), 1e-12f);
            va[t][r][0] *= sc; va[t][r][1] *= sc;
            s_nb[wrow0 + r][lane]      = (_Float16)va[t][r][0];
            s_nb[wrow0 + r][64 + lane] = (_Float16)va[t][r][1];
        }

        // ---- Sx agg from registers ----
        {
            float a0 = 0.f, a1v = 0.f;
            int cur = __shfl(sv[t], 0);
            int cf  = __shfl(fl[t], 0);
#pragma unroll
            for (int r = 0; r < 16; ++r) {
                a0 += va[t][r][0]; a1v += va[t][r][1];
                const int nxt = (r < 15) ? __shfl(sv[t], r + 1) : -2;
                if (nxt != cur) {
                    if (cur >= 0) {
                        float* d = &Sx[(size_t)cur * F + lane];
                        if (cf) { d[0] = a0; d[64] = a1v; }
                        else    { atomicAdd(d, a0); atomicAdd(d + 64, a1v); }
                    }
                    a0 = 0.f; a1v = 0.f; cur = nxt;
                    if (r < 15) cf = __shfl(fl[t], r + 1);
                }
            }
        }
        __syncthreads();   // (1) A-tile ready

        // ---- GEMM1: cols [w*64,(w+1)*64); A re-read from s_nb ----
        {
            const int colbase = w * 64 + mrow;
            float bj1[4];
#pragma unroll
            for (int ct = 0; ct < 4; ++ct) bj1[ct] = b1[colbase + ct * 16];

            f16x8 b[4], bn[4];
#pragma unroll
            for (int kk = 0; kk < 4; ++kk)
                b[kk] = *(const f16x8*)&W1t[(size_t)colbase * F + kk * 32 + kgrp * 8];

#pragma unroll
            for (int ct = 0; ct < 4; ++ct) {
                const int col = colbase + ct * 16;
                if (ct < 3) {
#pragma unroll
                    for (int kk = 0; kk < 4; ++kk)
                        bn[kk] = *(const f16x8*)&W1t[(size_t)(col + 16) * F + kk * 32 + kgrp * 8];
                }
                f32x4 acc[4];
#pragma unroll
                for (int m = 0; m < 4; ++m) acc[m] = (f32x4){0.f, 0.f, 0.f, 0.f};
                __builtin_amdgcn_s_setprio(1);
#pragma unroll
                for (int m = 0; m < 4; ++m) {
                    f16x8 a[4];
#pragma unroll
                    for (int kk = 0; kk < 4; ++kk)
                        a[kk] = *(const f16x8*)&s_nb[m * 16 + mrow][kk * 32 + kgrp * 8];
#pragma unroll
                    for (int kk = 0; kk < 4; ++kk)
                        acc[m] = __builtin_amdgcn_mfma_f32_16x16x32_f16(a[kk], b[kk], acc[m], 0, 0, 0);
                }
                __builtin_amdgcn_s_setprio(0);
#pragma unroll
                for (int m = 0; m < 4; ++m)
#pragma unroll
                    for (int q = 0; q < 4; ++q)
                        s_nh[m * 16 + kgrp * 4 + q][col] = (_Float16)(acc[m][q] + bj1[ct]);
#pragma unroll
                for (int kk = 0; kk < 4; ++kk) b[kk] = bn[kk];
            }
        }
        __syncthreads();   // (2) n_h ready

        // ---- S2 agg (own window rows of s_nh; relu on read) ----
#pragma unroll
        for (int half = 0; half < 2; ++half) {
            const int c0 = half * 128 + 2 * lane;
            float a0 = 0.f, a1v = 0.f;
            int cur = __shfl(sv[t], 0);
            int cf  = __shfl(fl[t], 0);
#pragma unroll
            for (int r = 0; r < 16; ++r) {
                const f16x2 pv = *(const f16x2*)&s_nh[wrow0 + r][c0];
                a0  += fmaxf((float)pv[0], 0.f);
                a1v += fmaxf((float)pv[1], 0.f);
                const int nxt = (r < 15) ? __shfl(sv[t], r + 1) : -2;
                if (nxt != cur) {
                    if (cur >= 0) {
                        float* d = &S2[(size_t)cur * H1 + c0];
                        if (cf) { *(float2*)d = make_float2(a0, a1v); }
                        else    { atomicAdd(d, a0); atomicAdd(d + 1, a1v); }
                    }
                    a0 = 0.f; a1v = 0.f; cur = nxt;
                    if (r < 15) cf = __shfl(fl[t], r + 1);
                }
            }
        }

        // ---- GEMM2: cols [w*32,(w+1)*32); A from s_nh; n_h2 -> s_nb ----
#pragma unroll
        for (int ct = 0; ct < 2; ++ct) {
            const int col = w * 32 + ct * 16 + mrow;
            const float bj = b2[col];
            f16x8 b[8];
#pragma unroll
            for (int k0 = 0; k0 < 8; ++k0)
                b[k0] = *(const f16x8*)&W2t[(size_t)col * H1 + k0 * 32 + kgrp * 8];
            f32x4 acc[4];
#pragma unroll
            for (int m = 0; m < 4; ++m) acc[m] = (f32x4){0.f, 0.f, 0.f, 0.f};
            __builtin_amdgcn_s_setprio(1);
#pragma unroll
            for (int m = 0; m < 4; ++m) {
                f16x8 a[8];
#pragma unroll
                for (int k0 = 0; k0 < 8; ++k0)
                    a[k0] = *(const f16x8*)&s_nh[m * 16 + mrow][k0 * 32 + kgrp * 8];
#pragma unroll
                for (int k0 = 0; k0 < 8; ++k0)
                    acc[m] = __builtin_amdgcn_mfma_f32_16x16x32_f16(a[k0], b[k0], acc[m], 0, 0, 0);
            }
            __builtin_amdgcn_s_setprio(0);
#pragma unroll
            for (int m = 0; m < 4; ++m)
#pragma unroll
                for (int q = 0; q < 4; ++q)
                    s_nb[m * 16 + kgrp * 4 + q][col] = (_Float16)(acc[m][q] + bj);
        }
        __syncthreads();   // (3) n_h2 ready

        // ---- S4 agg (own window rows of s_nb; relu on read) ----
        {
            const int c0 = 2 * lane;
            float a0 = 0.f, a1v = 0.f;
            int cur = __shfl(sv[t], 0);
            int cf  = __shfl(fl[t], 0);
#pragma unroll
            for (int r = 0; r < 16; ++r) {
                const f16x2 pv = *(const f16x2*)&s_nb[wrow0 + r][c0];
                a0  += fmaxf((float)pv[0], 0.f);
                a1v += fmaxf((float)pv[1], 0.f);
                const int nxt = (r < 15) ? __shfl(sv[t], r + 1) : -2;
                if (nxt != cur) {
                    if (cur >= 0) {
                        float* d = &S4[(size_t)cur * H2 + c0];
                        if (cf) { *(float2*)d = make_float2(a0, a1v); }
                        else    { atomicAdd(d, a0); atomicAdd(d + 1, a1v); }
                    }
                    a0 = 0.f; a1v = 0.f; cur = nxt;
                    if (r < 15) cf = __shfl(fl[t], r + 1);
                }
            }
        }
        __syncthreads();   // (4) s_nb/s_nh free for next tile
    }
}

// ---------------------------------------------------------------------------
// Node kernel v7 (unchanged): 4 waves x 16 nodes, zero barriers, MFMA.
// ---------------------------------------------------------------------------
__global__ __launch_bounds__(256, 2) void node_kernel7(
    const float* __restrict__ x,
    const _Float16* __restrict__ W1t, const float* __restrict__ b1,
    const _Float16* __restrict__ W2t, const float* __restrict__ b2,
    const _Float16* __restrict__ Wct, const float* __restrict__ bc,
    const float* __restrict__ Sx, const float* __restrict__ S2,
    const float* __restrict__ S4, const int* __restrict__ start,
    float* __restrict__ out, int N)
{
    __shared__ _Float16 s_a[4][32][264];

    const int tid  = threadIdx.x;
    const int lane = tid & 63;
    const int w    = tid >> 6;
    const int n0   = blockIdx.x * 64 + w * 16;
    const int mrow = lane & 15;
    const int kgrp = lane >> 4;

#pragma unroll
    for (int r = 0; r < 16; ++r) {
        const int n = n0 + r;
        float v0 = 0.f, v1 = 0.f, u0 = 0.f, u1 = 0.f;
        if (n < N) {
            v0 = x[(size_t)n * F + lane];
            v1 = x[(size_t)n * F + 64 + lane];
            u0 = Sx[(size_t)n * F + lane];
            u1 = Sx[(size_t)n * F + 64 + lane];
        }
        const float ss = wave_sum64(v0 * v0 + v1 * v1);
        const float sc = 1.0f / fmaxf(sqrtf(ss), 1e-12f);
        s_a[w][r][lane]           = (_Float16)(v0 * sc);
        s_a[w][r][64 + lane]      = (_Float16)(v1 * sc);
        s_a[w][16 + r][lane]      = (_Float16)u0;
        s_a[w][16 + r][64 + lane] = (_Float16)u1;
    }

    float cntq[4];
#pragma unroll
    for (int q = 0; q < 4; ++q) {
        const int n = n0 + kgrp * 4 + q;
        cntq[q] = (n < N) ? (float)(start[n + 1] - start[n]) : 0.f;
    }

    asm volatile("s_waitcnt lgkmcnt(0)" ::: "memory");
    __builtin_amdgcn_sched_barrier(0);

    f16x8 aA[2][4];
#pragma unroll
    for (int m = 0; m < 2; ++m)
#pragma unroll
        for (int kk = 0; kk < 4; ++kk)
            aA[m][kk] = *(const f16x8*)&s_a[w][m * 16 + mrow][kk * 32 + kgrp * 8];

#pragma unroll
    for (int n = 0; n < 16; ++n) {
        const int col = n * 16 + mrow;
        f32x4 accH = {0.f, 0.f, 0.f, 0.f};
        f32x4 accS = {0.f, 0.f, 0.f, 0.f};
#pragma unroll
        for (int kk = 0; kk < 4; ++kk) {
            const f16x8 b = *(const f16x8*)&W1t[(size_t)col * F + kk * 32 + kgrp * 8];
            accH = __builtin_amdgcn_mfma_f32_16x16x32_f16(aA[0][kk], b, accH, 0, 0, 0);
            accS = __builtin_amdgcn_mfma_f32_16x16x32_f16(aA[1][kk], b, accS, 0, 0, 0);
        }
        const float bj = b1[col];
#pragma unroll
        for (int q = 0; q < 4; ++q) {
            const int row = kgrp * 4 + q;
            const int n_  = n0 + row;
            const float h  = accH[q] + bj;
            const float S1 = accS[q] + cntq[q] * bj;
            const float x1 = fmaxf(h + 0.9f * S1, 0.f);
            const float s2v = (n_ < N) ? S2[(size_t)n_ * H1 + col] : 0.f;
            const float x2 = 0.9f * (x1 + s2v) + 0.1f * h;
            s_a[w][row][col]      = (_Float16)x2;
            s_a[w][16 + row][col] = (_Float16)S1;
        }
    }

    asm volatile("s_waitcnt lgkmcnt(0)" ::: "memory");
    __builtin_amdgcn_sched_barrier(0);

    f16x8 aB[2][8];
#pragma unroll
    for (int m = 0; m < 2; ++m)
#pragma unroll
        for (int k0 = 0; k0 < 8; ++k0)
            aB[m][k0] = *(const f16x8*)&s_a[w][m * 16 + mrow][k0 * 32 + kgrp * 8];

#pragma unroll
    for (int n = 0; n < 8; ++n) {
        const int col = n * 16 + mrow;
        f32x4 accH = {0.f, 0.f, 0.f, 0.f};
        f32x4 accS = {0.f, 0.f, 0.f, 0.f};
#pragma unroll
        for (int k0 = 0; k0 < 8; ++k0) {
            const f16x8 b = *(const f16x8*)&W2t[(size_t)col * H1 + k0 * 32 + kgrp * 8];
            accH = __builtin_amdgcn_mfma_f32_16x16x32_f16(aB[0][k0], b, accH, 0, 0, 0);
            accS = __builtin_amdgcn_mfma_f32_16x16x32_f16(aB[1][k0], b, accS, 0, 0, 0);
        }
        const float bj = b2[col];
#pragma unroll
        for (int q = 0; q < 4; ++q) {
            const int row = kgrp * 4 + q;
            const int n_  = n0 + row;
            const float h2 = accH[q] + bj;
            const float S3 = accS[q] + cntq[q] * bj;
            const float x3 = fmaxf(h2 + 0.9f * S3, 0.f);
            const float s4v = (n_ < N) ? S4[(size_t)n_ * H2 + col] : 0.f;
            s_a[w][row][col] = (_Float16)(0.9f * (x3 + s4v) + 0.1f * h2);
        }
    }

    asm volatile("s_waitcnt lgkmcnt(0)" ::: "memory");
    __builtin_amdgcn_sched_barrier(0);

    f16x8 aC[4];
#pragma unroll
    for (int kk = 0; kk < 4; ++kk)
        aC[kk] = *(const f16x8*)&s_a[w][mrow][kk * 32 + kgrp * 8];

#pragma unroll
    for (int n = 0; n < 3; ++n) {
        const int col = n * 16 + mrow;
        f32x4 acc = {0.f, 0.f, 0.f, 0.f};
#pragma unroll
        for (int kk = 0; kk < 4; ++kk) {
            const f16x8 b = *(const f16x8*)&Wct[(size_t)col * F + kk * 32 + kgrp * 8];
            acc = __builtin_amdgcn_mfma_f32_16x16x32_f16(aC[kk], b, acc, 0, 0, 0);
        }
        if (col < C) {
            const float bcc = bc[col];
#pragma unroll
            for (int q = 0; q < 4; ++q) {
                const int n_ = n0 + kgrp * 4 + q;
                if (n_ < N) out[(size_t)n_ * C + col] = acc[q] + bcc;
            }
        }
    }
}

extern "C" void kernel_launch(void* const* d_in, const int* in_sizes, int n_in,
                              void* d_out, int out_size, void* d_ws, size_t ws_size,
                              hipStream_t stream) {
    const float* x   = (const float*)d_in[0];
    const float* nbx = (const float*)d_in[1];
    const float* W1  = (const float*)d_in[2];
    const float* b1  = (const float*)d_in[3];
    const float* W2  = (const float*)d_in[4];
    const float* b2  = (const float*)d_in[5];
    const float* Wc  = (const float*)d_in[6];
    const float* bc  = (const float*)d_in[7];
    const int*   seg = (const int*)d_in[8];

    const int N = in_sizes[0] / F;   // 50000
    const int E = in_sizes[8];       // 600000
    float* out = (float*)d_out;

    float* Sx    = (float*)d_ws;
    float* S2    = Sx + (size_t)N * F;
    float* S4    = S2 + (size_t)N * H1;
    int*   hist  = (int*)(S4 + (size_t)N * H2);
    int*   cursor= hist + N;
    int*   bsum  = cursor + N;
    int*   start = bsum + 256;
    int*   ord   = start + (N + 1);
    char*  wrest = (char*)(ord + E);
    _Float16* W1t = (_Float16*)(((uintptr_t)wrest + 15) & ~(uintptr_t)15);
    _Float16* W2t = W1t + (size_t)H1 * F;
    _Float16* Wct = W2t + (size_t)H2 * H1;

    const size_t zero_bytes = ((size_t)N * (F + H1 + H2)) * 4 + (size_t)N * 8 + 1024;
    hipMemsetAsync(d_ws, 0, zero_bytes, stream);

    prep_weights<<<128, 256, 0, stream>>>(W1, W2, Wc, W1t, W2t, Wct);

    const int B = (N + 255) / 256;
    k_hist   <<<(E + 255) / 256, 256, 0, stream>>>(seg, hist, E);
    k_scan1  <<<B, 256, 0, stream>>>(hist, bsum, N);
    k_scan2  <<<1, 256, 0, stream>>>(bsum, B);
    k_scan3  <<<B, 256, 0, stream>>>(hist, bsum, start, cursor, N, E);
    k_scatter<<<(E + 255) / 256, 256, 0, stream>>>(seg, start, cursor, ord, E);

    edge_kernel9<<<(E + 127) / 128, 256, 0, stream>>>(
        nbx, seg, ord, start, W1t, b1, W2t, b2, Sx, S2, S4, E);
    node_kernel7<<<(N + 63) / 64, 256, 0, stream>>>(
        x, W1t, b1, W2t, b2, Wct, bc, Sx, S2, S4, start, out, N);
}